// Round 8
// baseline (1656.689 us; speedup 1.0000x reference)
//
#include <hip/hip_runtime.h>
#include <stdint.h>

typedef __bf16 bf16;
typedef __bf16 bf16x4 __attribute__((ext_vector_type(4)));
typedef __bf16 bf16x8 __attribute__((ext_vector_type(8)));
typedef float f32x4 __attribute__((ext_vector_type(4)));

#define MFMA16(a, b, c) __builtin_amdgcn_mfma_f32_16x16x32_bf16((a), (b), (c), 0, 0, 0)

static constexpr int NB = 4;      // batch
static constexpr int NH = 16;     // heads
static constexpr int SL = 2048;   // seq len
static constexpr int HD = 64;     // head dim
static constexpr int ED = 1024;   // embed
static constexpr int MR = NB * SL; // 8192 rows

__device__ __forceinline__ void gl_lds16(const void* g, void* l) {
    __builtin_amdgcn_global_load_lds(
        (const __attribute__((address_space(1))) unsigned int*)g,
        (__attribute__((address_space(3))) unsigned int*)l, 16, 0, 0);
}

// ------------------- f32 -> bf16 hi/lo split -------------------
__global__ void k_split(const float* __restrict__ src, bf16* __restrict__ hi,
                        bf16* __restrict__ lo, int n4) {
    int i = blockIdx.x * blockDim.x + threadIdx.x;
    if (i >= n4) return;
    const float4 v = ((const float4*)src)[i];
    float vv[4] = {v.x, v.y, v.z, v.w};
    bf16x4 hv, lv;
#pragma unroll
    for (int e = 0; e < 4; ++e) {
        bf16 h = (bf16)vv[e];
        hv[e] = h;
        lv[e] = (bf16)(vv[e] - (float)h);
    }
    ((bf16x4*)hi)[i] = hv;
    ((bf16x4*)lo)[i] = lv;
}

// ------------------- QKV projection GEMM (hi/lo inputs, bf16 outputs) -------------------
__global__ __launch_bounds__(256) void k_qkv_gemm(
    const bf16* __restrict__ xh, const bf16* __restrict__ xl,
    const bf16* __restrict__ wh, const bf16* __restrict__ wl,
    const float* __restrict__ bq, const float* __restrict__ bk,
    const float* __restrict__ bv,
    bf16* __restrict__ qh, bf16* __restrict__ kh, bf16* __restrict__ vh)
{
    __shared__ __attribute__((aligned(16))) bf16 As[2][128 * 32];
    __shared__ __attribute__((aligned(16))) bf16 Bs[2][128 * 32];

    const int z  = blockIdx.z;           // 0=q,1=k,2=v
    const int m0 = blockIdx.x * 128;
    const int n0 = blockIdx.y * 128;
    const int tid = threadIdx.x, wave = tid >> 6, lane = tid & 63;
    const int wr = wave >> 1, wc = wave & 1;
    const int fr = lane & 15, fq = lane >> 4;
    const bf16* Wh = wh + (size_t)z * ED * ED;
    const bf16* Wl = wl + (size_t)z * ED * ED;

    const f32x4 z4 = {0.f, 0.f, 0.f, 0.f};
    f32x4 acc[4][4];
#pragma unroll
    for (int i = 0; i < 4; ++i)
#pragma unroll
        for (int j = 0; j < 4; ++j) acc[i][j] = z4;

#pragma unroll 1
    for (int kk = 0; kk < ED; kk += 32) {
#pragma unroll
        for (int r = 0; r < 2; ++r) {
            const int chunk = r * 256 + tid;
            const int row = chunk >> 2, c8 = (chunk & 3) * 8;
            const size_t ax = (size_t)(m0 + row) * ED + kk + c8;
            const size_t bx = (size_t)(n0 + row) * ED + kk + c8;
            const int db = (r * 256 + wave * 64) * 8;   // wave-uniform LDS base
            gl_lds16(xh + ax, &As[0][db]);
            gl_lds16(xl + ax, &As[1][db]);
            gl_lds16(Wh + bx, &Bs[0][db]);
            gl_lds16(Wl + bx, &Bs[1][db]);
        }
        __syncthreads();
        bf16x8 af[4][2], bfg[4][2];
#pragma unroll
        for (int i = 0; i < 4; ++i) {
            const int arow = wr * 64 + i * 16 + fr;
            af[i][0] = *(const bf16x8*)&As[0][arow * 32 + fq * 8];
            af[i][1] = *(const bf16x8*)&As[1][arow * 32 + fq * 8];
            const int brow = wc * 64 + i * 16 + fr;
            bfg[i][0] = *(const bf16x8*)&Bs[0][brow * 32 + fq * 8];
            bfg[i][1] = *(const bf16x8*)&Bs[1][brow * 32 + fq * 8];
        }
#pragma unroll
        for (int mi = 0; mi < 4; ++mi)
#pragma unroll
            for (int ni = 0; ni < 4; ++ni) {
                acc[mi][ni] = MFMA16(af[mi][0], bfg[ni][0], acc[mi][ni]);
                acc[mi][ni] = MFMA16(af[mi][0], bfg[ni][1], acc[mi][ni]);
                acc[mi][ni] = MFMA16(af[mi][1], bfg[ni][0], acc[mi][ni]);
            }
        __syncthreads();
    }

    const float* bias = (z == 0) ? bq : (z == 1) ? bk : bv;
#pragma unroll
    for (int mi = 0; mi < 4; ++mi) {
#pragma unroll
        for (int ni = 0; ni < 4; ++ni) {
            const int col = n0 + wc * 64 + ni * 16 + fr;
            const int hh = col >> 6, dd = col & 63;
#pragma unroll
            for (int j = 0; j < 4; ++j) {
                const int row = m0 + wr * 64 + mi * 16 + fq * 4 + j;
                float v = acc[mi][ni][j] + bias[col];
                const int nb = row >> 11, li = row & (SL - 1);
                const size_t off = (((size_t)nb * NH + hh) * SL + li) * HD + dd;
                if (z == 0) {
                    qh[off] = (bf16)(v * 0.125f);      // head_dim^-0.5
                } else if (z == 1) {
                    kh[off] = (bf16)v;
                } else {
                    vh[off] = (bf16)v;
                }
            }
        }
    }
}

// ------------------- output projection GEMM (hi/lo) -------------------
__global__ __launch_bounds__(256) void k_out_gemm(
    const bf16* __restrict__ ah, const bf16* __restrict__ al,
    const bf16* __restrict__ wh, const bf16* __restrict__ wl,
    const float* __restrict__ bo, float* __restrict__ out)
{
    __shared__ __attribute__((aligned(16))) bf16 As[2][128 * 32];
    __shared__ __attribute__((aligned(16))) bf16 Bs[2][128 * 32];

    const int m0 = blockIdx.x * 128;
    const int n0 = blockIdx.y * 128;
    const int tid = threadIdx.x, wave = tid >> 6, lane = tid & 63;
    const int wr = wave >> 1, wc = wave & 1;
    const int fr = lane & 15, fq = lane >> 4;

    const f32x4 z4 = {0.f, 0.f, 0.f, 0.f};
    f32x4 acc[4][4];
#pragma unroll
    for (int i = 0; i < 4; ++i)
#pragma unroll
        for (int j = 0; j < 4; ++j) acc[i][j] = z4;

#pragma unroll 1
    for (int kk = 0; kk < ED; kk += 32) {
#pragma unroll
        for (int r = 0; r < 2; ++r) {
            const int chunk = r * 256 + tid;
            const int row = chunk >> 2, c8 = (chunk & 3) * 8;
            const size_t ax = (size_t)(m0 + row) * ED + kk + c8;
            const size_t bx = (size_t)(n0 + row) * ED + kk + c8;
            const int db = (r * 256 + wave * 64) * 8;
            gl_lds16(ah + ax, &As[0][db]);
            gl_lds16(al + ax, &As[1][db]);
            gl_lds16(wh + bx, &Bs[0][db]);
            gl_lds16(wl + bx, &Bs[1][db]);
        }
        __syncthreads();
        bf16x8 af[4][2], bfg[4][2];
#pragma unroll
        for (int i = 0; i < 4; ++i) {
            const int arow = wr * 64 + i * 16 + fr;
            af[i][0] = *(const bf16x8*)&As[0][arow * 32 + fq * 8];
            af[i][1] = *(const bf16x8*)&As[1][arow * 32 + fq * 8];
            const int brow = wc * 64 + i * 16 + fr;
            bfg[i][0] = *(const bf16x8*)&Bs[0][brow * 32 + fq * 8];
            bfg[i][1] = *(const bf16x8*)&Bs[1][brow * 32 + fq * 8];
        }
#pragma unroll
        for (int mi = 0; mi < 4; ++mi)
#pragma unroll
            for (int ni = 0; ni < 4; ++ni) {
                acc[mi][ni] = MFMA16(af[mi][0], bfg[ni][0], acc[mi][ni]);
                acc[mi][ni] = MFMA16(af[mi][0], bfg[ni][1], acc[mi][ni]);
                acc[mi][ni] = MFMA16(af[mi][1], bfg[ni][0], acc[mi][ni]);
            }
        __syncthreads();
    }

#pragma unroll
    for (int mi = 0; mi < 4; ++mi)
#pragma unroll
        for (int ni = 0; ni < 4; ++ni) {
            const int col = n0 + wc * 64 + ni * 16 + fr;
#pragma unroll
            for (int j = 0; j < 4; ++j) {
                const int row = m0 + wr * 64 + mi * 16 + fq * 4 + j;
                out[(size_t)row * ED + col] = acc[mi][ni][j] + bo[col];
            }
        }
}

// ------------------- flash attention v3: single-buffer 24KB LDS, 5 blocks/CU -------------------
// Stage {K gl_lds, Vs<-vr} -> barrier(drain) -> issue V/bias(kt+1) -> compute -> barrier.
// Block map: per XCD 2 heads; n fastest so 4 batches share each bias tile in L2.
__global__ __launch_bounds__(256, 5) void k_flash(
    const bf16* __restrict__ qh, const bf16* __restrict__ kh,
    const bf16* __restrict__ vh,
    const float* __restrict__ bias, const int* __restrict__ mask,
    bf16* __restrict__ ch, bf16* __restrict__ cl,
    float* __restrict__ mrow, float* __restrict__ srow)
{
    __shared__ __attribute__((aligned(16))) bf16 Ks[64 * 64];     // [key][d] swz
    __shared__ __attribute__((aligned(16))) bf16 Vs[64 * 64];     // [d][key] swz
    __shared__ __attribute__((aligned(16))) bf16 Ws[4][16 * 64];  // per-wave P, swz

    // block map: xcd gets 2 heads; within: qt sweeps, n fastest (bias L2 reuse)
    const int bid = blockIdx.x;
    const int xcd = bid & 7, local = bid >> 3;
    const int h = xcd * 2 + (local >> 7);
    const int rem = local & 127;
    const int qt = rem >> 2, n = rem & 3;

    const int tid = threadIdx.x, wave = tid >> 6, lane = tid & 63;
    const int fr = lane & 15, fq = lane >> 4;
    const int frx = fr & 7;
    const int q0 = qt * 64;
    const size_t hoff = ((size_t)n * NH + h) * SL * HD;
    const f32x4 z4 = {0.f, 0.f, 0.f, 0.f};

    bf16x8 qf0, qf1;
    {
        const size_t qb = hoff + (size_t)(q0 + wave * 16 + fr) * HD + fq * 8;
        qf0 = *(const bf16x8*)(qh + qb);
        qf1 = *(const bf16x8*)(qh + qb + 32);
    }

    f32x4 o[4];
#pragma unroll
    for (int f = 0; f < 4; ++f) o[f] = z4;
    float mj[4] = {-3e38f, -3e38f, -3e38f, -3e38f};
    float sj[4] = {0.f, 0.f, 0.f, 0.f};
    size_t brow[4];
#pragma unroll
    for (int j = 0; j < 4; ++j)
        brow[j] = ((size_t)h * SL + q0 + wave * 16 + fq * 4 + j) * SL;
    const int* mkb = mask + n * SL;

    // ---- prologue: V(0), bias(0), mask(0) into regs ----
    bf16x8 vr0 = *(const bf16x8*)(vh + hoff + (size_t)lane * HD + wave * 8);
    bf16x8 vr1 = *(const bf16x8*)(vh + hoff + (size_t)lane * HD + (wave + 4) * 8);
    float bc[4][4];
    int mkc[4];
#pragma unroll
    for (int nf = 0; nf < 4; ++nf) {
        mkc[nf] = mkb[nf * 16 + fr];
#pragma unroll
        for (int j = 0; j < 4; ++j)
            bc[nf][j] = bias[brow[j] + nf * 16 + fr];
    }

#pragma unroll 1
    for (int kt = 0; kt < 32; ++kt) {
        const int kp1 = (kt < 31) ? kt + 1 : 31;

        // ---- stage phase (buffers free: all readers passed last barrier) ----
#pragma unroll
        for (int i = 0; i < 2; ++i) {
            const int li = i * 256 + tid;
            const int r = li >> 3, s = li & 7;
            gl_lds16(kh + hoff + (size_t)(kt * 64 + r) * HD + (s ^ (r & 7)) * 8,
                     &Ks[(i * 256 + wave * 64) * 8]);
        }
#pragma unroll
        for (int e = 0; e < 8; ++e) {
            const int d0 = wave * 8 + e, d1 = (wave + 4) * 8 + e;
            Vs[d0 * 64 + (((lane >> 3) ^ (d0 & 7)) << 3) + (lane & 7)] = vr0[e];
            Vs[d1 * 64 + (((lane >> 3) ^ (d1 & 7)) << 3) + (lane & 7)] = vr1[e];
        }
        __syncthreads();   // drains K arrival + Vs writes

        // ---- issue next-tile register prefetches (hidden under compute) ----
        vr0 = *(const bf16x8*)(vh + hoff + (size_t)(kp1 * 64 + lane) * HD + wave * 8);
        vr1 = *(const bf16x8*)(vh + hoff + (size_t)(kp1 * 64 + lane) * HD + (wave + 4) * 8);
        float bn[4][4];
        int mkn[4];
#pragma unroll
        for (int nf = 0; nf < 4; ++nf) {
            mkn[nf] = mkb[kp1 * 64 + nf * 16 + fr];
#pragma unroll
            for (int j = 0; j < 4; ++j)
                bn[nf][j] = bias[brow[j] + kp1 * 64 + nf * 16 + fr];
        }

        // ---- compute: QK^T ----
        f32x4 sf[4];
        __builtin_amdgcn_s_setprio(1);
#pragma unroll
        for (int nf = 0; nf < 4; ++nf) {
            const bf16* kp = &Ks[(nf * 16 + fr) * 64];
            const bf16x8 b0 = *(const bf16x8*)&kp[(fq ^ frx) * 8];
            const bf16x8 b1 = *(const bf16x8*)&kp[((fq + 4) ^ frx) * 8];
            f32x4 a = z4;
            a = MFMA16(qf0, b0, a);
            a = MFMA16(qf1, b1, a);
            sf[nf] = a;
        }
        __builtin_amdgcn_s_setprio(0);

        // bias + mask (current tile, prefetched last iteration)
#pragma unroll
        for (int nf = 0; nf < 4; ++nf) {
            const bool mk = mkc[nf] != 0;
#pragma unroll
            for (int j = 0; j < 4; ++j) {
                float s = sf[nf][j] + bc[nf][j];
                sf[nf][j] = mk ? -1e30f : s;
            }
        }
        // online softmax (rows wave-local; 16-lane butterfly)
        float tmax[4];
#pragma unroll
        for (int j = 0; j < 4; ++j)
            tmax[j] = fmaxf(fmaxf(sf[0][j], sf[1][j]), fmaxf(sf[2][j], sf[3][j]));
#pragma unroll
        for (int d = 1; d < 16; d <<= 1)
#pragma unroll
            for (int j = 0; j < 4; ++j)
                tmax[j] = fmaxf(tmax[j], __shfl_xor(tmax[j], d));
        float scale[4];
#pragma unroll
        for (int j = 0; j < 4; ++j) {
            const float mn = fmaxf(mj[j], tmax[j]);
            scale[j] = __expf(mj[j] - mn);
            mj[j] = mn;
        }
        float rs[4] = {0.f, 0.f, 0.f, 0.f};
#pragma unroll
        for (int nf = 0; nf < 4; ++nf)
#pragma unroll
            for (int j = 0; j < 4; ++j) {
                const float w = __expf(sf[nf][j] - mj[j]);
                sf[nf][j] = w;
                rs[j] += w;
            }
#pragma unroll
        for (int d = 1; d < 16; d <<= 1)
#pragma unroll
            for (int j = 0; j < 4; ++j)
                rs[j] += __shfl_xor(rs[j], d);
#pragma unroll
        for (int j = 0; j < 4; ++j) sj[j] = sj[j] * scale[j] + rs[j];
#pragma unroll
        for (int f = 0; f < 4; ++f)
#pragma unroll
            for (int j = 0; j < 4; ++j) o[f][j] *= scale[j];

        // P -> per-wave swizzled LDS tile (wave-local: no barrier needed)
#pragma unroll
        for (int nf = 0; nf < 4; ++nf)
#pragma unroll
            for (int j = 0; j < 4; ++j) {
                const int row = fq * 4 + j, col = nf * 16 + fr;
                Ws[wave][row * 64 + (((col >> 3) ^ (row & 7)) << 3) + (fr & 7)] =
                    (bf16)sf[nf][j];
            }
        const bf16* wp = &Ws[wave][fr * 64];
        const bf16x8 wa0 = *(const bf16x8*)&wp[(fq ^ frx) * 8];
        const bf16x8 wa1 = *(const bf16x8*)&wp[((fq + 4) ^ frx) * 8];
        __builtin_amdgcn_s_setprio(1);
#pragma unroll
        for (int f = 0; f < 4; ++f) {
            const bf16* vp = &Vs[(f * 16 + fr) * 64];
            const bf16x8 vb0 = *(const bf16x8*)&vp[(fq ^ frx) * 8];
            const bf16x8 vb1 = *(const bf16x8*)&vp[((fq + 4) ^ frx) * 8];
            o[f] = MFMA16(wa0, vb0, o[f]);
            o[f] = MFMA16(wa1, vb1, o[f]);
        }
        __builtin_amdgcn_s_setprio(0);

        // rotate prefetched scalars (waits on bn arrival = end of compute)
#pragma unroll
        for (int nf = 0; nf < 4; ++nf) {
            mkc[nf] = mkn[nf];
#pragma unroll
            for (int j = 0; j < 4; ++j) bc[nf][j] = bn[nf][j];
        }
        __syncthreads();   // all readers done before next stage overwrites
    }

    // epilogue: context (hi/lo) + row stats
#pragma unroll
    for (int j = 0; j < 4; ++j) {
        const float inv = 1.0f / sj[j];
        const int row = n * SL + q0 + wave * 16 + fq * 4 + j;
#pragma unroll
        for (int f = 0; f < 4; ++f) {
            const float v = o[f][j] * inv;
            const size_t off = (size_t)row * ED + h * HD + f * 16 + fr;
            const bf16 hv = (bf16)v;
            ch[off] = hv;
            cl[off] = (bf16)(v - (float)hv);
        }
    }
    if (fr == 0) {
#pragma unroll
        for (int j = 0; j < 4; ++j) {
            const int r = q0 + wave * 16 + fq * 4 + j;
            mrow[((size_t)n * NH + h) * SL + r] = mj[j];
            srow[((size_t)n * NH + h) * SL + r] = sj[j];
        }
    }
}

// ------------------- head-averaged weights v3: LDS-staged, reg accumulator -------------------
__global__ __launch_bounds__(256) void k_avg(
    const bf16* __restrict__ qh, const bf16* __restrict__ kh,
    const float* __restrict__ bias, const int* __restrict__ mask,
    const float* __restrict__ mrow, const float* __restrict__ srow,
    float* __restrict__ avg)
{
    __shared__ __attribute__((aligned(16))) bf16 Qs[2][64 * 64];  // 8KB x2
    __shared__ __attribute__((aligned(16))) bf16 Ks2[2][32 * 64]; // 4KB x2

    const int qt = blockIdx.x, kt = blockIdx.y;
    const int tid = threadIdx.x, wave = tid >> 6, lane = tid & 63;
    const int fr = lane & 15, fq = lane >> 4;
    const int frx = fr & 7;
    const int q0 = qt * 64, k0 = kt * 32;
    const int qr = q0 + wave * 16;
    const f32x4 z4 = {0.f, 0.f, 0.f, 0.f};

    f32x4 acc[4][2];
#pragma unroll
    for (int nn = 0; nn < 4; ++nn)
#pragma unroll
        for (int nf = 0; nf < 2; ++nf) acc[nn][nf] = z4;

    bool mk[4][2];
#pragma unroll
    for (int nn = 0; nn < 4; ++nn)
#pragma unroll
        for (int nf = 0; nf < 2; ++nf)
            mk[nn][nf] = mask[nn * SL + k0 + nf * 16 + fr] != 0;

    auto stage = [&](int hh, int nn2, int b) {
        const bf16* qb = qh + (((size_t)nn2 * NH + hh) * SL + q0) * HD;
        const bf16* kb = kh + (((size_t)nn2 * NH + hh) * SL + k0) * HD;
#pragma unroll
        for (int i = 0; i < 2; ++i) {
            const int li = i * 256 + tid;
            const int r = li >> 3, s = li & 7;
            gl_lds16(qb + (size_t)r * HD + (s ^ (r & 7)) * 8,
                     &Qs[b][(i * 256 + wave * 64) * 8]);
        }
        {
            const int r = tid >> 3, s = tid & 7;
            gl_lds16(kb + (size_t)r * HD + (s ^ (r & 7)) * 8,
                     &Ks2[b][(wave * 64) * 8]);
        }
    };

    stage(0, 0, 0);
    __syncthreads();

    int cur = 0;
#pragma unroll 1
    for (int h = 0; h < NH; ++h) {
        float bfr[2][4];
#pragma unroll
        for (int nf = 0; nf < 2; ++nf)
#pragma unroll
            for (int j = 0; j < 4; ++j)
                bfr[nf][j] = bias[((size_t)h * SL + qr + fq * 4 + j) * SL + k0 + nf * 16 + fr];

#pragma unroll
        for (int nn = 0; nn < 4; ++nn) {
            const int ih = h * 4 + nn;
            const int nxt = cur ^ 1;
            if (ih < 63) stage((ih + 1) >> 2, (ih + 1) & 3, nxt);

            const size_t sidx = ((size_t)nn * NH + h) * SL + qr + fq * 4;
            const f32x4 mv = *(const f32x4*)(mrow + sidx);
            const f32x4 sv = *(const f32x4*)(srow + sidx);
            float t2[2][4];
#pragma unroll
            for (int j = 0; j < 4; ++j) {
                const float lg = __logf(16.0f * sv[j]);
#pragma unroll
                for (int nf = 0; nf < 2; ++nf)
                    t2[nf][j] = mk[nn][nf] ? -1e30f : (bfr[nf][j] - mv[j] - lg);
            }

            const bf16* qp = &Qs[cur][(wave * 16 + fr) * 64];
            const bf16x8 qf0 = *(const bf16x8*)&qp[(fq ^ frx) * 8];
            const bf16x8 qf1 = *(const bf16x8*)&qp[((fq + 4) ^ frx) * 8];
#pragma unroll
            for (int nf = 0; nf < 2; ++nf) {
                const bf16* kp = &Ks2[cur][(nf * 16 + fr) * 64];
                const bf16x8 b0 = *(const bf16x8*)&kp[(fq ^ frx) * 8];
                const bf16x8 b1 = *(const bf16x8*)&kp[((fq + 4) ^ frx) * 8];
                f32x4 a = z4;
                a = MFMA16(qf0, b0, a);
                a = MFMA16(qf1, b1, a);
#pragma unroll
                for (int j = 0; j < 4; ++j)
                    acc[nn][nf][j] += __expf(a[j] + t2[nf][j]);
            }
            __syncthreads();
            cur = nxt;
        }
    }

#pragma unroll
    for (int nn = 0; nn < 4; ++nn)
#pragma unroll
        for (int j = 0; j < 4; ++j) {
            const size_t rowoff = ((size_t)nn * SL + qr + fq * 4 + j) * SL;
#pragma unroll
            for (int nf = 0; nf < 2; ++nf)
                avg[rowoff + k0 + nf * 16 + fr] = acc[nn][nf][j];
        }
}

// ------------------- launcher -------------------
extern "C" void kernel_launch(void* const* d_in, const int* in_sizes, int n_in,
                              void* d_out, int out_size, void* d_ws, size_t ws_size,
                              hipStream_t stream)
{
    (void)in_sizes; (void)n_in; (void)out_size; (void)ws_size;
    const float* query = (const float*)d_in[0];
    const float* bias  = (const float*)d_in[1];
    const int* mask = (const int*)d_in[2];
    const float* Wq = (const float*)d_in[3];
    const float* bq = (const float*)d_in[4];
    const float* Wk = (const float*)d_in[5];
    const float* bk = (const float*)d_in[6];
    const float* Wv = (const float*)d_in[7];
    const float* bv = (const float*)d_in[8];
    const float* Wo = (const float*)d_in[9];
    const float* bo = (const float*)d_in[10];
    float* out0 = (float*)d_out;                      // [N,L,E]
    float* out1 = out0 + (size_t)MR * ED;             // [N,L,L]

    char* p = (char*)d_ws;
    auto carve = [&](size_t bytes) {
        char* r = p;
        p += (bytes + 255) & ~(size_t)255;
        return r;
    };
    const size_t QKVB = (size_t)NB * NH * SL * HD * 2;   // 16.78 MB
    bf16* xh = (bf16*)carve((size_t)MR * ED * 2);
    bf16* xl = (bf16*)carve((size_t)MR * ED * 2);
    bf16* wh = (bf16*)carve((size_t)4 * ED * ED * 2);
    bf16* wl = (bf16*)carve((size_t)4 * ED * ED * 2);
    bf16* qh = (bf16*)carve(QKVB);
    bf16* kh = (bf16*)carve(QKVB);
    bf16* vh = (bf16*)carve(QKVB);
    float* mrow = (float*)carve((size_t)NB * NH * SL * 4);
    float* srow = (float*)carve((size_t)NB * NH * SL * 4);
    bf16* ch = (bf16*)carve((size_t)MR * ED * 2);
    bf16* cl = (bf16*)carve((size_t)MR * ED * 2);

    // 1. split inputs to hi/lo bf16
    {
        const int n4 = MR * ED / 4;
        k_split<<<(n4 + 255) / 256, 256, 0, stream>>>(query, xh, xl, n4);
        const int w4 = ED * ED / 4;
        const float* Ws4[4] = {Wq, Wk, Wv, Wo};
        for (int i = 0; i < 4; ++i)
            k_split<<<(w4 + 255) / 256, 256, 0, stream>>>(
                Ws4[i], wh + (size_t)i * ED * ED, wl + (size_t)i * ED * ED, w4);
    }
    // 2. QKV projections
    k_qkv_gemm<<<dim3(MR / 128, ED / 128, 3), 256, 0, stream>>>(
        xh, xl, wh, wl, bq, bk, bv, qh, kh, vh);
    // 3. flash attention + row stats + context
    k_flash<<<dim3(2048), 256, 0, stream>>>(
        qh, kh, vh, bias, mask, ch, cl, mrow, srow);
    // 4. head-averaged attention weights
    k_avg<<<dim3(SL / 64, SL / 32), 256, 0, stream>>>(
        qh, kh, bias, mask, mrow, srow, out1);
    // 5. output projection
    k_out_gemm<<<dim3(MR / 128, ED / 128), 256, 0, stream>>>(
        ch, cl, wh + (size_t)3 * ED * ED, wl + (size_t)3 * ED * ED, bo, out0);
}

// Round 9
// 1022.612 us; speedup vs baseline: 1.6201x; 1.6201x over previous
//
#include <hip/hip_runtime.h>
#include <stdint.h>

typedef __bf16 bf16;
typedef __bf16 bf16x4 __attribute__((ext_vector_type(4)));
typedef __bf16 bf16x8 __attribute__((ext_vector_type(8)));
typedef float f32x4 __attribute__((ext_vector_type(4)));

#define MFMA16(a, b, c) __builtin_amdgcn_mfma_f32_16x16x32_bf16((a), (b), (c), 0, 0, 0)

static constexpr int NB = 4;      // batch
static constexpr int NH = 16;     // heads
static constexpr int SL = 2048;   // seq len
static constexpr int HD = 64;     // head dim
static constexpr int ED = 1024;   // embed
static constexpr int MR = NB * SL; // 8192 rows

__device__ __forceinline__ void gl_lds16(const void* g, void* l) {
    __builtin_amdgcn_global_load_lds(
        (const __attribute__((address_space(1))) unsigned int*)g,
        (__attribute__((address_space(3))) unsigned int*)l, 16, 0, 0);
}

// ------------------- f32 -> bf16 hi/lo split -------------------
__global__ void k_split(const float* __restrict__ src, bf16* __restrict__ hi,
                        bf16* __restrict__ lo, int n4) {
    int i = blockIdx.x * blockDim.x + threadIdx.x;
    if (i >= n4) return;
    const float4 v = ((const float4*)src)[i];
    float vv[4] = {v.x, v.y, v.z, v.w};
    bf16x4 hv, lv;
#pragma unroll
    for (int e = 0; e < 4; ++e) {
        bf16 h = (bf16)vv[e];
        hv[e] = h;
        lv[e] = (bf16)(vv[e] - (float)h);
    }
    ((bf16x4*)hi)[i] = hv;
    ((bf16x4*)lo)[i] = lv;
}

// ------------------- QKV projection GEMM (hi/lo inputs, bf16 outputs) -------------------
__global__ __launch_bounds__(256) void k_qkv_gemm(
    const bf16* __restrict__ xh, const bf16* __restrict__ xl,
    const bf16* __restrict__ wh, const bf16* __restrict__ wl,
    const float* __restrict__ bq, const float* __restrict__ bk,
    const float* __restrict__ bv,
    bf16* __restrict__ qh, bf16* __restrict__ kh, bf16* __restrict__ vh)
{
    __shared__ __attribute__((aligned(16))) bf16 As[2][128 * 32];
    __shared__ __attribute__((aligned(16))) bf16 Bs[2][128 * 32];

    const int z  = blockIdx.z;           // 0=q,1=k,2=v
    const int m0 = blockIdx.x * 128;
    const int n0 = blockIdx.y * 128;
    const int tid = threadIdx.x, wave = tid >> 6, lane = tid & 63;
    const int wr = wave >> 1, wc = wave & 1;
    const int fr = lane & 15, fq = lane >> 4;
    const bf16* Wh = wh + (size_t)z * ED * ED;
    const bf16* Wl = wl + (size_t)z * ED * ED;

    const f32x4 z4 = {0.f, 0.f, 0.f, 0.f};
    f32x4 acc[4][4];
#pragma unroll
    for (int i = 0; i < 4; ++i)
#pragma unroll
        for (int j = 0; j < 4; ++j) acc[i][j] = z4;

#pragma unroll 1
    for (int kk = 0; kk < ED; kk += 32) {
#pragma unroll
        for (int r = 0; r < 2; ++r) {
            const int chunk = r * 256 + tid;
            const int row = chunk >> 2, c8 = (chunk & 3) * 8;
            const size_t ax = (size_t)(m0 + row) * ED + kk + c8;
            const size_t bx = (size_t)(n0 + row) * ED + kk + c8;
            const int db = (r * 256 + wave * 64) * 8;   // wave-uniform LDS base
            gl_lds16(xh + ax, &As[0][db]);
            gl_lds16(xl + ax, &As[1][db]);
            gl_lds16(Wh + bx, &Bs[0][db]);
            gl_lds16(Wl + bx, &Bs[1][db]);
        }
        __syncthreads();
        bf16x8 af[4][2], bfg[4][2];
#pragma unroll
        for (int i = 0; i < 4; ++i) {
            const int arow = wr * 64 + i * 16 + fr;
            af[i][0] = *(const bf16x8*)&As[0][arow * 32 + fq * 8];
            af[i][1] = *(const bf16x8*)&As[1][arow * 32 + fq * 8];
            const int brow = wc * 64 + i * 16 + fr;
            bfg[i][0] = *(const bf16x8*)&Bs[0][brow * 32 + fq * 8];
            bfg[i][1] = *(const bf16x8*)&Bs[1][brow * 32 + fq * 8];
        }
#pragma unroll
        for (int mi = 0; mi < 4; ++mi)
#pragma unroll
            for (int ni = 0; ni < 4; ++ni) {
                acc[mi][ni] = MFMA16(af[mi][0], bfg[ni][0], acc[mi][ni]);
                acc[mi][ni] = MFMA16(af[mi][0], bfg[ni][1], acc[mi][ni]);
                acc[mi][ni] = MFMA16(af[mi][1], bfg[ni][0], acc[mi][ni]);
            }
        __syncthreads();
    }

    const float* bias = (z == 0) ? bq : (z == 1) ? bk : bv;
#pragma unroll
    for (int mi = 0; mi < 4; ++mi) {
#pragma unroll
        for (int ni = 0; ni < 4; ++ni) {
            const int col = n0 + wc * 64 + ni * 16 + fr;
            const int hh = col >> 6, dd = col & 63;
#pragma unroll
            for (int j = 0; j < 4; ++j) {
                const int row = m0 + wr * 64 + mi * 16 + fq * 4 + j;
                float v = acc[mi][ni][j] + bias[col];
                const int nb = row >> 11, li = row & (SL - 1);
                const size_t off = (((size_t)nb * NH + hh) * SL + li) * HD + dd;
                if (z == 0) {
                    qh[off] = (bf16)(v * 0.125f);      // head_dim^-0.5
                } else if (z == 1) {
                    kh[off] = (bf16)v;
                } else {
                    vh[off] = (bf16)v;
                }
            }
        }
    }
}

// ------------------- output projection GEMM (hi/lo) -------------------
__global__ __launch_bounds__(256) void k_out_gemm(
    const bf16* __restrict__ ah, const bf16* __restrict__ al,
    const bf16* __restrict__ wh, const bf16* __restrict__ wl,
    const float* __restrict__ bo, float* __restrict__ out)
{
    __shared__ __attribute__((aligned(16))) bf16 As[2][128 * 32];
    __shared__ __attribute__((aligned(16))) bf16 Bs[2][128 * 32];

    const int m0 = blockIdx.x * 128;
    const int n0 = blockIdx.y * 128;
    const int tid = threadIdx.x, wave = tid >> 6, lane = tid & 63;
    const int wr = wave >> 1, wc = wave & 1;
    const int fr = lane & 15, fq = lane >> 4;

    const f32x4 z4 = {0.f, 0.f, 0.f, 0.f};
    f32x4 acc[4][4];
#pragma unroll
    for (int i = 0; i < 4; ++i)
#pragma unroll
        for (int j = 0; j < 4; ++j) acc[i][j] = z4;

#pragma unroll 1
    for (int kk = 0; kk < ED; kk += 32) {
#pragma unroll
        for (int r = 0; r < 2; ++r) {
            const int chunk = r * 256 + tid;
            const int row = chunk >> 2, c8 = (chunk & 3) * 8;
            const size_t ax = (size_t)(m0 + row) * ED + kk + c8;
            const size_t bx = (size_t)(n0 + row) * ED + kk + c8;
            const int db = (r * 256 + wave * 64) * 8;
            gl_lds16(ah + ax, &As[0][db]);
            gl_lds16(al + ax, &As[1][db]);
            gl_lds16(wh + bx, &Bs[0][db]);
            gl_lds16(wl + bx, &Bs[1][db]);
        }
        __syncthreads();
        bf16x8 af[4][2], bfg[4][2];
#pragma unroll
        for (int i = 0; i < 4; ++i) {
            const int arow = wr * 64 + i * 16 + fr;
            af[i][0] = *(const bf16x8*)&As[0][arow * 32 + fq * 8];
            af[i][1] = *(const bf16x8*)&As[1][arow * 32 + fq * 8];
            const int brow = wc * 64 + i * 16 + fr;
            bfg[i][0] = *(const bf16x8*)&Bs[0][brow * 32 + fq * 8];
            bfg[i][1] = *(const bf16x8*)&Bs[1][brow * 32 + fq * 8];
        }
#pragma unroll
        for (int mi = 0; mi < 4; ++mi)
#pragma unroll
            for (int ni = 0; ni < 4; ++ni) {
                acc[mi][ni] = MFMA16(af[mi][0], bfg[ni][0], acc[mi][ni]);
                acc[mi][ni] = MFMA16(af[mi][0], bfg[ni][1], acc[mi][ni]);
                acc[mi][ni] = MFMA16(af[mi][1], bfg[ni][0], acc[mi][ni]);
            }
        __syncthreads();
    }

#pragma unroll
    for (int mi = 0; mi < 4; ++mi)
#pragma unroll
        for (int ni = 0; ni < 4; ++ni) {
            const int col = n0 + wc * 64 + ni * 16 + fr;
#pragma unroll
            for (int j = 0; j < 4; ++j) {
                const int row = m0 + wr * 64 + mi * 16 + fq * 4 + j;
                out[(size_t)row * ED + col] = acc[mi][ni][j] + bo[col];
            }
        }
}

// ------------------- flash attention v3.1: single-buffer 24KB LDS -------------------
// Same as v3 but launch_bounds(256,4): VGPR cap 128 (natural ~88, no spills),
// 4 waves/SIMD -> 4 blocks/CU -> ~50% occupancy.
__global__ __launch_bounds__(256, 4) void k_flash(
    const bf16* __restrict__ qh, const bf16* __restrict__ kh,
    const bf16* __restrict__ vh,
    const float* __restrict__ bias, const int* __restrict__ mask,
    bf16* __restrict__ ch, bf16* __restrict__ cl,
    float* __restrict__ mrow, float* __restrict__ srow)
{
    __shared__ __attribute__((aligned(16))) bf16 Ks[64 * 64];     // [key][d] swz
    __shared__ __attribute__((aligned(16))) bf16 Vs[64 * 64];     // [d][key] swz
    __shared__ __attribute__((aligned(16))) bf16 Ws[4][16 * 64];  // per-wave P, swz

    // block map: xcd gets 2 heads; within: qt sweeps, n fastest (bias L2 reuse)
    const int bid = blockIdx.x;
    const int xcd = bid & 7, local = bid >> 3;
    const int h = xcd * 2 + (local >> 7);
    const int rem = local & 127;
    const int qt = rem >> 2, n = rem & 3;

    const int tid = threadIdx.x, wave = tid >> 6, lane = tid & 63;
    const int fr = lane & 15, fq = lane >> 4;
    const int frx = fr & 7;
    const int q0 = qt * 64;
    const size_t hoff = ((size_t)n * NH + h) * SL * HD;
    const f32x4 z4 = {0.f, 0.f, 0.f, 0.f};

    bf16x8 qf0, qf1;
    {
        const size_t qb = hoff + (size_t)(q0 + wave * 16 + fr) * HD + fq * 8;
        qf0 = *(const bf16x8*)(qh + qb);
        qf1 = *(const bf16x8*)(qh + qb + 32);
    }

    f32x4 o[4];
#pragma unroll
    for (int f = 0; f < 4; ++f) o[f] = z4;
    float mj[4] = {-3e38f, -3e38f, -3e38f, -3e38f};
    float sj[4] = {0.f, 0.f, 0.f, 0.f};
    size_t brow[4];
#pragma unroll
    for (int j = 0; j < 4; ++j)
        brow[j] = ((size_t)h * SL + q0 + wave * 16 + fq * 4 + j) * SL;
    const int* mkb = mask + n * SL;

    // ---- prologue: V(0), bias(0), mask(0) into regs ----
    bf16x8 vr0 = *(const bf16x8*)(vh + hoff + (size_t)lane * HD + wave * 8);
    bf16x8 vr1 = *(const bf16x8*)(vh + hoff + (size_t)lane * HD + (wave + 4) * 8);
    float bc[4][4];
    int mkc[4];
#pragma unroll
    for (int nf = 0; nf < 4; ++nf) {
        mkc[nf] = mkb[nf * 16 + fr];
#pragma unroll
        for (int j = 0; j < 4; ++j)
            bc[nf][j] = bias[brow[j] + nf * 16 + fr];
    }

#pragma unroll 1
    for (int kt = 0; kt < 32; ++kt) {
        const int kp1 = (kt < 31) ? kt + 1 : 31;

        // ---- stage phase (buffers free: all readers passed last barrier) ----
#pragma unroll
        for (int i = 0; i < 2; ++i) {
            const int li = i * 256 + tid;
            const int r = li >> 3, s = li & 7;
            gl_lds16(kh + hoff + (size_t)(kt * 64 + r) * HD + (s ^ (r & 7)) * 8,
                     &Ks[(i * 256 + wave * 64) * 8]);
        }
#pragma unroll
        for (int e = 0; e < 8; ++e) {
            const int d0 = wave * 8 + e, d1 = (wave + 4) * 8 + e;
            Vs[d0 * 64 + (((lane >> 3) ^ (d0 & 7)) << 3) + (lane & 7)] = vr0[e];
            Vs[d1 * 64 + (((lane >> 3) ^ (d1 & 7)) << 3) + (lane & 7)] = vr1[e];
        }
        __syncthreads();   // drains K arrival + Vs writes

        // ---- issue next-tile register prefetches (hidden under compute) ----
        vr0 = *(const bf16x8*)(vh + hoff + (size_t)(kp1 * 64 + lane) * HD + wave * 8);
        vr1 = *(const bf16x8*)(vh + hoff + (size_t)(kp1 * 64 + lane) * HD + (wave + 4) * 8);
        float bn[4][4];
        int mkn[4];
#pragma unroll
        for (int nf = 0; nf < 4; ++nf) {
            mkn[nf] = mkb[kp1 * 64 + nf * 16 + fr];
#pragma unroll
            for (int j = 0; j < 4; ++j)
                bn[nf][j] = bias[brow[j] + kp1 * 64 + nf * 16 + fr];
        }

        // ---- compute: QK^T ----
        f32x4 sf[4];
        __builtin_amdgcn_s_setprio(1);
#pragma unroll
        for (int nf = 0; nf < 4; ++nf) {
            const bf16* kp = &Ks[(nf * 16 + fr) * 64];
            const bf16x8 b0 = *(const bf16x8*)&kp[(fq ^ frx) * 8];
            const bf16x8 b1 = *(const bf16x8*)&kp[((fq + 4) ^ frx) * 8];
            f32x4 a = z4;
            a = MFMA16(qf0, b0, a);
            a = MFMA16(qf1, b1, a);
            sf[nf] = a;
        }
        __builtin_amdgcn_s_setprio(0);

        // bias + mask (current tile, prefetched last iteration)
#pragma unroll
        for (int nf = 0; nf < 4; ++nf) {
            const bool mk = mkc[nf] != 0;
#pragma unroll
            for (int j = 0; j < 4; ++j) {
                float s = sf[nf][j] + bc[nf][j];
                sf[nf][j] = mk ? -1e30f : s;
            }
        }
        // online softmax (rows wave-local; 16-lane butterfly)
        float tmax[4];
#pragma unroll
        for (int j = 0; j < 4; ++j)
            tmax[j] = fmaxf(fmaxf(sf[0][j], sf[1][j]), fmaxf(sf[2][j], sf[3][j]));
#pragma unroll
        for (int d = 1; d < 16; d <<= 1)
#pragma unroll
            for (int j = 0; j < 4; ++j)
                tmax[j] = fmaxf(tmax[j], __shfl_xor(tmax[j], d));
        float scale[4];
#pragma unroll
        for (int j = 0; j < 4; ++j) {
            const float mn = fmaxf(mj[j], tmax[j]);
            scale[j] = __expf(mj[j] - mn);
            mj[j] = mn;
        }
        float rs[4] = {0.f, 0.f, 0.f, 0.f};
#pragma unroll
        for (int nf = 0; nf < 4; ++nf)
#pragma unroll
            for (int j = 0; j < 4; ++j) {
                const float w = __expf(sf[nf][j] - mj[j]);
                sf[nf][j] = w;
                rs[j] += w;
            }
#pragma unroll
        for (int d = 1; d < 16; d <<= 1)
#pragma unroll
            for (int j = 0; j < 4; ++j)
                rs[j] += __shfl_xor(rs[j], d);
#pragma unroll
        for (int j = 0; j < 4; ++j) sj[j] = sj[j] * scale[j] + rs[j];
#pragma unroll
        for (int f = 0; f < 4; ++f)
#pragma unroll
            for (int j = 0; j < 4; ++j) o[f][j] *= scale[j];

        // P -> per-wave swizzled LDS tile (wave-local: no barrier needed)
#pragma unroll
        for (int nf = 0; nf < 4; ++nf)
#pragma unroll
            for (int j = 0; j < 4; ++j) {
                const int row = fq * 4 + j, col = nf * 16 + fr;
                Ws[wave][row * 64 + (((col >> 3) ^ (row & 7)) << 3) + (fr & 7)] =
                    (bf16)sf[nf][j];
            }
        const bf16* wp = &Ws[wave][fr * 64];
        const bf16x8 wa0 = *(const bf16x8*)&wp[(fq ^ frx) * 8];
        const bf16x8 wa1 = *(const bf16x8*)&wp[((fq + 4) ^ frx) * 8];
        __builtin_amdgcn_s_setprio(1);
#pragma unroll
        for (int f = 0; f < 4; ++f) {
            const bf16* vp = &Vs[(f * 16 + fr) * 64];
            const bf16x8 vb0 = *(const bf16x8*)&vp[(fq ^ frx) * 8];
            const bf16x8 vb1 = *(const bf16x8*)&vp[((fq + 4) ^ frx) * 8];
            o[f] = MFMA16(wa0, vb0, o[f]);
            o[f] = MFMA16(wa1, vb1, o[f]);
        }
        __builtin_amdgcn_s_setprio(0);

        // rotate prefetched scalars (waits on bn arrival = end of compute)
#pragma unroll
        for (int nf = 0; nf < 4; ++nf) {
            mkc[nf] = mkn[nf];
#pragma unroll
            for (int j = 0; j < 4; ++j) bc[nf][j] = bn[nf][j];
        }
        __syncthreads();   // all readers done before next stage overwrites
    }

    // epilogue: context (hi/lo) + row stats
#pragma unroll
    for (int j = 0; j < 4; ++j) {
        const float inv = 1.0f / sj[j];
        const int row = n * SL + q0 + wave * 16 + fq * 4 + j;
#pragma unroll
        for (int f = 0; f < 4; ++f) {
            const float v = o[f][j] * inv;
            const size_t off = (size_t)row * ED + h * HD + f * 16 + fr;
            const bf16 hv = (bf16)v;
            ch[off] = hv;
            cl[off] = (bf16)(v - (float)hv);
        }
    }
    if (fr == 0) {
#pragma unroll
        for (int j = 0; j < 4; ++j) {
            const int r = q0 + wave * 16 + fq * 4 + j;
            mrow[((size_t)n * NH + h) * SL + r] = mj[j];
            srow[((size_t)n * NH + h) * SL + r] = sj[j];
        }
    }
}

// ------------------- head-averaged weights v3: LDS-staged, reg accumulator -------------------
__global__ __launch_bounds__(256) void k_avg(
    const bf16* __restrict__ qh, const bf16* __restrict__ kh,
    const float* __restrict__ bias, const int* __restrict__ mask,
    const float* __restrict__ mrow, const float* __restrict__ srow,
    float* __restrict__ avg)
{
    __shared__ __attribute__((aligned(16))) bf16 Qs[2][64 * 64];  // 8KB x2
    __shared__ __attribute__((aligned(16))) bf16 Ks2[2][32 * 64]; // 4KB x2

    const int qt = blockIdx.x, kt = blockIdx.y;
    const int tid = threadIdx.x, wave = tid >> 6, lane = tid & 63;
    const int fr = lane & 15, fq = lane >> 4;
    const int frx = fr & 7;
    const int q0 = qt * 64, k0 = kt * 32;
    const int qr = q0 + wave * 16;
    const f32x4 z4 = {0.f, 0.f, 0.f, 0.f};

    f32x4 acc[4][2];
#pragma unroll
    for (int nn = 0; nn < 4; ++nn)
#pragma unroll
        for (int nf = 0; nf < 2; ++nf) acc[nn][nf] = z4;

    bool mk[4][2];
#pragma unroll
    for (int nn = 0; nn < 4; ++nn)
#pragma unroll
        for (int nf = 0; nf < 2; ++nf)
            mk[nn][nf] = mask[nn * SL + k0 + nf * 16 + fr] != 0;

    auto stage = [&](int hh, int nn2, int b) {
        const bf16* qb = qh + (((size_t)nn2 * NH + hh) * SL + q0) * HD;
        const bf16* kb = kh + (((size_t)nn2 * NH + hh) * SL + k0) * HD;
#pragma unroll
        for (int i = 0; i < 2; ++i) {
            const int li = i * 256 + tid;
            const int r = li >> 3, s = li & 7;
            gl_lds16(qb + (size_t)r * HD + (s ^ (r & 7)) * 8,
                     &Qs[b][(i * 256 + wave * 64) * 8]);
        }
        {
            const int r = tid >> 3, s = tid & 7;
            gl_lds16(kb + (size_t)r * HD + (s ^ (r & 7)) * 8,
                     &Ks2[b][(wave * 64) * 8]);
        }
    };

    stage(0, 0, 0);
    __syncthreads();

    int cur = 0;
#pragma unroll 1
    for (int h = 0; h < NH; ++h) {
        float bfr[2][4];
#pragma unroll
        for (int nf = 0; nf < 2; ++nf)
#pragma unroll
            for (int j = 0; j < 4; ++j)
                bfr[nf][j] = bias[((size_t)h * SL + qr + fq * 4 + j) * SL + k0 + nf * 16 + fr];

#pragma unroll
        for (int nn = 0; nn < 4; ++nn) {
            const int ih = h * 4 + nn;
            const int nxt = cur ^ 1;
            if (ih < 63) stage((ih + 1) >> 2, (ih + 1) & 3, nxt);

            const size_t sidx = ((size_t)nn * NH + h) * SL + qr + fq * 4;
            const f32x4 mv = *(const f32x4*)(mrow + sidx);
            const f32x4 sv = *(const f32x4*)(srow + sidx);
            float t2[2][4];
#pragma unroll
            for (int j = 0; j < 4; ++j) {
                const float lg = __logf(16.0f * sv[j]);
#pragma unroll
                for (int nf = 0; nf < 2; ++nf)
                    t2[nf][j] = mk[nn][nf] ? -1e30f : (bfr[nf][j] - mv[j] - lg);
            }

            const bf16* qp = &Qs[cur][(wave * 16 + fr) * 64];
            const bf16x8 qf0 = *(const bf16x8*)&qp[(fq ^ frx) * 8];
            const bf16x8 qf1 = *(const bf16x8*)&qp[((fq + 4) ^ frx) * 8];
#pragma unroll
            for (int nf = 0; nf < 2; ++nf) {
                const bf16* kp = &Ks2[cur][(nf * 16 + fr) * 64];
                const bf16x8 b0 = *(const bf16x8*)&kp[(fq ^ frx) * 8];
                const bf16x8 b1 = *(const bf16x8*)&kp[((fq + 4) ^ frx) * 8];
                f32x4 a = z4;
                a = MFMA16(qf0, b0, a);
                a = MFMA16(qf1, b1, a);
#pragma unroll
                for (int j = 0; j < 4; ++j)
                    acc[nn][nf][j] += __expf(a[j] + t2[nf][j]);
            }
            __syncthreads();
            cur = nxt;
        }
    }

#pragma unroll
    for (int nn = 0; nn < 4; ++nn)
#pragma unroll
        for (int j = 0; j < 4; ++j) {
            const size_t rowoff = ((size_t)nn * SL + qr + fq * 4 + j) * SL;
#pragma unroll
            for (int nf = 0; nf < 2; ++nf)
                avg[rowoff + k0 + nf * 16 + fr] = acc[nn][nf][j];
        }
}

// ------------------- launcher -------------------
extern "C" void kernel_launch(void* const* d_in, const int* in_sizes, int n_in,
                              void* d_out, int out_size, void* d_ws, size_t ws_size,
                              hipStream_t stream)
{
    (void)in_sizes; (void)n_in; (void)out_size; (void)ws_size;
    const float* query = (const float*)d_in[0];
    const float* bias  = (const float*)d_in[1];
    const int* mask = (const int*)d_in[2];
    const float* Wq = (const float*)d_in[3];
    const float* bq = (const float*)d_in[4];
    const float* Wk = (const float*)d_in[5];
    const float* bk = (const float*)d_in[6];
    const float* Wv = (const float*)d_in[7];
    const float* bv = (const float*)d_in[8];
    const float* Wo = (const float*)d_in[9];
    const float* bo = (const float*)d_in[10];
    float* out0 = (float*)d_out;                      // [N,L,E]
    float* out1 = out0 + (size_t)MR * ED;             // [N,L,L]

    char* p = (char*)d_ws;
    auto carve = [&](size_t bytes) {
        char* r = p;
        p += (bytes + 255) & ~(size_t)255;
        return r;
    };
    const size_t QKVB = (size_t)NB * NH * SL * HD * 2;   // 16.78 MB
    bf16* xh = (bf16*)carve((size_t)MR * ED * 2);
    bf16* xl = (bf16*)carve((size_t)MR * ED * 2);
    bf16* wh = (bf16*)carve((size_t)4 * ED * ED * 2);
    bf16* wl = (bf16*)carve((size_t)4 * ED * ED * 2);
    bf16* qh = (bf16*)carve(QKVB);
    bf16* kh = (bf16*)carve(QKVB);
    bf16* vh = (bf16*)carve(QKVB);
    float* mrow = (float*)carve((size_t)NB * NH * SL * 4);
    float* srow = (float*)carve((size_t)NB * NH * SL * 4);
    bf16* ch = (bf16*)carve((size_t)MR * ED * 2);
    bf16* cl = (bf16*)carve((size_t)MR * ED * 2);

    // 1. split inputs to hi/lo bf16
    {
        const int n4 = MR * ED / 4;
        k_split<<<(n4 + 255) / 256, 256, 0, stream>>>(query, xh, xl, n4);
        const int w4 = ED * ED / 4;
        const float* Ws4[4] = {Wq, Wk, Wv, Wo};
        for (int i = 0; i < 4; ++i)
            k_split<<<(w4 + 255) / 256, 256, 0, stream>>>(
                Ws4[i], wh + (size_t)i * ED * ED, wl + (size_t)i * ED * ED, w4);
    }
    // 2. QKV projections
    k_qkv_gemm<<<dim3(MR / 128, ED / 128, 3), 256, 0, stream>>>(
        xh, xl, wh, wl, bq, bk, bv, qh, kh, vh);
    // 3. flash attention + row stats + context
    k_flash<<<dim3(2048), 256, 0, stream>>>(
        qh, kh, vh, bias, mask, ch, cl, mrow, srow);
    // 4. head-averaged attention weights
    k_avg<<<dim3(SL / 64, SL / 32), 256, 0, stream>>>(
        qh, kh, bias, mask, mrow, srow, out1);
    // 5. output projection
    k_out_gemm<<<dim3(MR / 128, ED / 128), 256, 0, stream>>>(
        ch, cl, wh + (size_t)3 * ED * ED, wl + (size_t)3 * ED * ED, bo, out0);
}

// Round 10
// 782.554 us; speedup vs baseline: 2.1170x; 1.3068x over previous
//
#include <hip/hip_runtime.h>
#include <stdint.h>

typedef __bf16 bf16;
typedef __bf16 bf16x4 __attribute__((ext_vector_type(4)));
typedef __bf16 bf16x8 __attribute__((ext_vector_type(8)));
typedef float f32x4 __attribute__((ext_vector_type(4)));

#define MFMA16(a, b, c) __builtin_amdgcn_mfma_f32_16x16x32_bf16((a), (b), (c), 0, 0, 0)

static constexpr int NB = 4;      // batch
static constexpr int NH = 16;     // heads
static constexpr int SL = 2048;   // seq len
static constexpr int HD = 64;     // head dim
static constexpr int ED = 1024;   // embed
static constexpr int MR = NB * SL; // 8192 rows

__device__ __forceinline__ void gl_lds16(const void* g, void* l) {
    __builtin_amdgcn_global_load_lds(
        (const __attribute__((address_space(1))) unsigned int*)g,
        (__attribute__((address_space(3))) unsigned int*)l, 16, 0, 0);
}

// ------------------- f32 -> bf16 hi/lo split -------------------
__global__ void k_split(const float* __restrict__ src, bf16* __restrict__ hi,
                        bf16* __restrict__ lo, int n4) {
    int i = blockIdx.x * blockDim.x + threadIdx.x;
    if (i >= n4) return;
    const float4 v = ((const float4*)src)[i];
    float vv[4] = {v.x, v.y, v.z, v.w};
    bf16x4 hv, lv;
#pragma unroll
    for (int e = 0; e < 4; ++e) {
        bf16 h = (bf16)vv[e];
        hv[e] = h;
        lv[e] = (bf16)(vv[e] - (float)h);
    }
    ((bf16x4*)hi)[i] = hv;
    ((bf16x4*)lo)[i] = lv;
}

// ------------------- QKV projection GEMM (hi/lo inputs, bf16 outputs) -------------------
__global__ __launch_bounds__(256) void k_qkv_gemm(
    const bf16* __restrict__ xh, const bf16* __restrict__ xl,
    const bf16* __restrict__ wh, const bf16* __restrict__ wl,
    const float* __restrict__ bq, const float* __restrict__ bk,
    const float* __restrict__ bv,
    bf16* __restrict__ qh, bf16* __restrict__ kh, bf16* __restrict__ vh)
{
    __shared__ __attribute__((aligned(16))) bf16 As[2][128 * 32];
    __shared__ __attribute__((aligned(16))) bf16 Bs[2][128 * 32];

    const int z  = blockIdx.z;           // 0=q,1=k,2=v
    const int m0 = blockIdx.x * 128;
    const int n0 = blockIdx.y * 128;
    const int tid = threadIdx.x, wave = tid >> 6, lane = tid & 63;
    const int wr = wave >> 1, wc = wave & 1;
    const int fr = lane & 15, fq = lane >> 4;
    const bf16* Wh = wh + (size_t)z * ED * ED;
    const bf16* Wl = wl + (size_t)z * ED * ED;

    const f32x4 z4 = {0.f, 0.f, 0.f, 0.f};
    f32x4 acc[4][4];
#pragma unroll
    for (int i = 0; i < 4; ++i)
#pragma unroll
        for (int j = 0; j < 4; ++j) acc[i][j] = z4;

#pragma unroll 1
    for (int kk = 0; kk < ED; kk += 32) {
#pragma unroll
        for (int r = 0; r < 2; ++r) {
            const int chunk = r * 256 + tid;
            const int row = chunk >> 2, c8 = (chunk & 3) * 8;
            const size_t ax = (size_t)(m0 + row) * ED + kk + c8;
            const size_t bx = (size_t)(n0 + row) * ED + kk + c8;
            const int db = (r * 256 + wave * 64) * 8;   // wave-uniform LDS base
            gl_lds16(xh + ax, &As[0][db]);
            gl_lds16(xl + ax, &As[1][db]);
            gl_lds16(Wh + bx, &Bs[0][db]);
            gl_lds16(Wl + bx, &Bs[1][db]);
        }
        __syncthreads();
        bf16x8 af[4][2], bfg[4][2];
#pragma unroll
        for (int i = 0; i < 4; ++i) {
            const int arow = wr * 64 + i * 16 + fr;
            af[i][0] = *(const bf16x8*)&As[0][arow * 32 + fq * 8];
            af[i][1] = *(const bf16x8*)&As[1][arow * 32 + fq * 8];
            const int brow = wc * 64 + i * 16 + fr;
            bfg[i][0] = *(const bf16x8*)&Bs[0][brow * 32 + fq * 8];
            bfg[i][1] = *(const bf16x8*)&Bs[1][brow * 32 + fq * 8];
        }
#pragma unroll
        for (int mi = 0; mi < 4; ++mi)
#pragma unroll
            for (int ni = 0; ni < 4; ++ni) {
                acc[mi][ni] = MFMA16(af[mi][0], bfg[ni][0], acc[mi][ni]);
                acc[mi][ni] = MFMA16(af[mi][0], bfg[ni][1], acc[mi][ni]);
                acc[mi][ni] = MFMA16(af[mi][1], bfg[ni][0], acc[mi][ni]);
            }
        __syncthreads();
    }

    const float* bias = (z == 0) ? bq : (z == 1) ? bk : bv;
#pragma unroll
    for (int mi = 0; mi < 4; ++mi) {
#pragma unroll
        for (int ni = 0; ni < 4; ++ni) {
            const int col = n0 + wc * 64 + ni * 16 + fr;
            const int hh = col >> 6, dd = col & 63;
#pragma unroll
            for (int j = 0; j < 4; ++j) {
                const int row = m0 + wr * 64 + mi * 16 + fq * 4 + j;
                float v = acc[mi][ni][j] + bias[col];
                const int nb = row >> 11, li = row & (SL - 1);
                const size_t off = (((size_t)nb * NH + hh) * SL + li) * HD + dd;
                if (z == 0) {
                    qh[off] = (bf16)(v * 0.125f);      // head_dim^-0.5
                } else if (z == 1) {
                    kh[off] = (bf16)v;
                } else {
                    vh[off] = (bf16)v;
                }
            }
        }
    }
}

// ------------------- output projection GEMM (hi/lo) -------------------
__global__ __launch_bounds__(256) void k_out_gemm(
    const bf16* __restrict__ ah, const bf16* __restrict__ al,
    const bf16* __restrict__ wh, const bf16* __restrict__ wl,
    const float* __restrict__ bo, float* __restrict__ out)
{
    __shared__ __attribute__((aligned(16))) bf16 As[2][128 * 32];
    __shared__ __attribute__((aligned(16))) bf16 Bs[2][128 * 32];

    const int m0 = blockIdx.x * 128;
    const int n0 = blockIdx.y * 128;
    const int tid = threadIdx.x, wave = tid >> 6, lane = tid & 63;
    const int wr = wave >> 1, wc = wave & 1;
    const int fr = lane & 15, fq = lane >> 4;

    const f32x4 z4 = {0.f, 0.f, 0.f, 0.f};
    f32x4 acc[4][4];
#pragma unroll
    for (int i = 0; i < 4; ++i)
#pragma unroll
        for (int j = 0; j < 4; ++j) acc[i][j] = z4;

#pragma unroll 1
    for (int kk = 0; kk < ED; kk += 32) {
#pragma unroll
        for (int r = 0; r < 2; ++r) {
            const int chunk = r * 256 + tid;
            const int row = chunk >> 2, c8 = (chunk & 3) * 8;
            const size_t ax = (size_t)(m0 + row) * ED + kk + c8;
            const size_t bx = (size_t)(n0 + row) * ED + kk + c8;
            const int db = (r * 256 + wave * 64) * 8;
            gl_lds16(ah + ax, &As[0][db]);
            gl_lds16(al + ax, &As[1][db]);
            gl_lds16(wh + bx, &Bs[0][db]);
            gl_lds16(wl + bx, &Bs[1][db]);
        }
        __syncthreads();
        bf16x8 af[4][2], bfg[4][2];
#pragma unroll
        for (int i = 0; i < 4; ++i) {
            const int arow = wr * 64 + i * 16 + fr;
            af[i][0] = *(const bf16x8*)&As[0][arow * 32 + fq * 8];
            af[i][1] = *(const bf16x8*)&As[1][arow * 32 + fq * 8];
            const int brow = wc * 64 + i * 16 + fr;
            bfg[i][0] = *(const bf16x8*)&Bs[0][brow * 32 + fq * 8];
            bfg[i][1] = *(const bf16x8*)&Bs[1][brow * 32 + fq * 8];
        }
#pragma unroll
        for (int mi = 0; mi < 4; ++mi)
#pragma unroll
            for (int ni = 0; ni < 4; ++ni) {
                acc[mi][ni] = MFMA16(af[mi][0], bfg[ni][0], acc[mi][ni]);
                acc[mi][ni] = MFMA16(af[mi][0], bfg[ni][1], acc[mi][ni]);
                acc[mi][ni] = MFMA16(af[mi][1], bfg[ni][0], acc[mi][ni]);
            }
        __syncthreads();
    }

#pragma unroll
    for (int mi = 0; mi < 4; ++mi)
#pragma unroll
        for (int ni = 0; ni < 4; ++ni) {
            const int col = n0 + wc * 64 + ni * 16 + fr;
#pragma unroll
            for (int j = 0; j < 4; ++j) {
                const int row = m0 + wr * 64 + mi * 16 + fq * 4 + j;
                out[(size_t)row * ED + col] = acc[mi][ni][j] + bo[col];
            }
        }
}

// ------------------- flash attention v4: Ks double-buffered, plain launch_bounds -------------------
// Per tile: {Vs<-vr} -> barrier -> {issue K(kt+1)->Ks[nxt], V(kt+1)->regs, bias(kt+1)->regs}
// -> compute on Ks[cur]/Vs -> barrier (K arrival drained under compute cover).
// 32KB LDS + natural ~90 VGPR -> 4 blocks/CU.
__global__ __launch_bounds__(256) void k_flash(
    const bf16* __restrict__ qh, const bf16* __restrict__ kh,
    const bf16* __restrict__ vh,
    const float* __restrict__ bias, const int* __restrict__ mask,
    bf16* __restrict__ ch, bf16* __restrict__ cl,
    float* __restrict__ mrow, float* __restrict__ srow)
{
    __shared__ __attribute__((aligned(16))) bf16 Ks[2][64 * 64];  // [key][d] swz, dbuf
    __shared__ __attribute__((aligned(16))) bf16 Vs[64 * 64];     // [d][key] swz
    __shared__ __attribute__((aligned(16))) bf16 Ws[4][16 * 64];  // per-wave P, swz

    // block map: xcd gets 2 heads; within: qt sweeps, n fastest (bias L2 reuse)
    const int bid = blockIdx.x;
    const int xcd = bid & 7, local = bid >> 3;
    const int h = xcd * 2 + (local >> 7);
    const int rem = local & 127;
    const int qt = rem >> 2, n = rem & 3;

    const int tid = threadIdx.x, wave = tid >> 6, lane = tid & 63;
    const int fr = lane & 15, fq = lane >> 4;
    const int frx = fr & 7;
    const int q0 = qt * 64;
    const size_t hoff = ((size_t)n * NH + h) * SL * HD;
    const f32x4 z4 = {0.f, 0.f, 0.f, 0.f};

    bf16x8 qf0, qf1;
    {
        const size_t qb = hoff + (size_t)(q0 + wave * 16 + fr) * HD + fq * 8;
        qf0 = *(const bf16x8*)(qh + qb);
        qf1 = *(const bf16x8*)(qh + qb + 32);
    }

    f32x4 o[4];
#pragma unroll
    for (int f = 0; f < 4; ++f) o[f] = z4;
    float mj[4] = {-3e38f, -3e38f, -3e38f, -3e38f};
    float sj[4] = {0.f, 0.f, 0.f, 0.f};
    size_t brow[4];
#pragma unroll
    for (int j = 0; j < 4; ++j)
        brow[j] = ((size_t)h * SL + q0 + wave * 16 + fq * 4 + j) * SL;
    const int* mkb = mask + n * SL;

    // ---- prologue: issue K(0)->Ks[0]; V(0)/bias(0)/mask(0) -> regs ----
#pragma unroll
    for (int i = 0; i < 2; ++i) {
        const int li = i * 256 + tid;
        const int r = li >> 3, s = li & 7;
        gl_lds16(kh + hoff + (size_t)r * HD + (s ^ (r & 7)) * 8,
                 &Ks[0][(i * 256 + wave * 64) * 8]);
    }
    bf16x8 vr0 = *(const bf16x8*)(vh + hoff + (size_t)lane * HD + wave * 8);
    bf16x8 vr1 = *(const bf16x8*)(vh + hoff + (size_t)lane * HD + (wave + 4) * 8);
    float bc[4][4];
    int mkc[4];
#pragma unroll
    for (int nf = 0; nf < 4; ++nf) {
        mkc[nf] = mkb[nf * 16 + fr];
#pragma unroll
        for (int j = 0; j < 4; ++j)
            bc[nf][j] = bias[brow[j] + nf * 16 + fr];
    }
    __syncthreads();   // drains K(0) (one-time exposed latency)

    int cur = 0;
#pragma unroll 1
    for (int kt = 0; kt < 32; ++kt) {
        const int nxt = cur ^ 1;
        const int kp1 = (kt < 31) ? kt + 1 : 31;

        // ---- A: Vs <- vr (V(kt)); readers of Vs(kt-1) passed last barrier ----
#pragma unroll
        for (int e = 0; e < 8; ++e) {
            const int d0 = wave * 8 + e, d1 = (wave + 4) * 8 + e;
            Vs[d0 * 64 + (((lane >> 3) ^ (d0 & 7)) << 3) + (lane & 7)] = vr0[e];
            Vs[d1 * 64 + (((lane >> 3) ^ (d1 & 7)) << 3) + (lane & 7)] = vr1[e];
        }
        __syncthreads();   // Vs visible (lgkm only; no vmem outstanding here)

        // ---- B: issue next-tile prefetches (covered by phase C compute) ----
#pragma unroll
        for (int i = 0; i < 2; ++i) {
            const int li = i * 256 + tid;
            const int r = li >> 3, s = li & 7;
            gl_lds16(kh + hoff + (size_t)(kp1 * 64 + r) * HD + (s ^ (r & 7)) * 8,
                     &Ks[nxt][(i * 256 + wave * 64) * 8]);
        }
        vr0 = *(const bf16x8*)(vh + hoff + (size_t)(kp1 * 64 + lane) * HD + wave * 8);
        vr1 = *(const bf16x8*)(vh + hoff + (size_t)(kp1 * 64 + lane) * HD + (wave + 4) * 8);
        float bn[4][4];
        int mkn[4];
#pragma unroll
        for (int nf = 0; nf < 4; ++nf) {
            mkn[nf] = mkb[kp1 * 64 + nf * 16 + fr];
#pragma unroll
            for (int j = 0; j < 4; ++j)
                bn[nf][j] = bias[brow[j] + kp1 * 64 + nf * 16 + fr];
        }

        // ---- C: compute QK^T on Ks[cur] ----
        f32x4 sf[4];
        __builtin_amdgcn_s_setprio(1);
#pragma unroll
        for (int nf = 0; nf < 4; ++nf) {
            const bf16* kp = &Ks[cur][(nf * 16 + fr) * 64];
            const bf16x8 b0 = *(const bf16x8*)&kp[(fq ^ frx) * 8];
            const bf16x8 b1 = *(const bf16x8*)&kp[((fq + 4) ^ frx) * 8];
            f32x4 a = z4;
            a = MFMA16(qf0, b0, a);
            a = MFMA16(qf1, b1, a);
            sf[nf] = a;
        }
        __builtin_amdgcn_s_setprio(0);

        // bias + mask (current tile, prefetched last iteration)
#pragma unroll
        for (int nf = 0; nf < 4; ++nf) {
            const bool mk = mkc[nf] != 0;
#pragma unroll
            for (int j = 0; j < 4; ++j) {
                float s = sf[nf][j] + bc[nf][j];
                sf[nf][j] = mk ? -1e30f : s;
            }
        }
        // online softmax (rows wave-local; 16-lane butterfly)
        float tmax[4];
#pragma unroll
        for (int j = 0; j < 4; ++j)
            tmax[j] = fmaxf(fmaxf(sf[0][j], sf[1][j]), fmaxf(sf[2][j], sf[3][j]));
#pragma unroll
        for (int d = 1; d < 16; d <<= 1)
#pragma unroll
            for (int j = 0; j < 4; ++j)
                tmax[j] = fmaxf(tmax[j], __shfl_xor(tmax[j], d));
        float scale[4];
#pragma unroll
        for (int j = 0; j < 4; ++j) {
            const float mn = fmaxf(mj[j], tmax[j]);
            scale[j] = __expf(mj[j] - mn);
            mj[j] = mn;
        }
        float rs[4] = {0.f, 0.f, 0.f, 0.f};
#pragma unroll
        for (int nf = 0; nf < 4; ++nf)
#pragma unroll
            for (int j = 0; j < 4; ++j) {
                const float w = __expf(sf[nf][j] - mj[j]);
                sf[nf][j] = w;
                rs[j] += w;
            }
#pragma unroll
        for (int d = 1; d < 16; d <<= 1)
#pragma unroll
            for (int j = 0; j < 4; ++j)
                rs[j] += __shfl_xor(rs[j], d);
#pragma unroll
        for (int j = 0; j < 4; ++j) sj[j] = sj[j] * scale[j] + rs[j];
#pragma unroll
        for (int f = 0; f < 4; ++f)
#pragma unroll
            for (int j = 0; j < 4; ++j) o[f][j] *= scale[j];

        // P -> per-wave swizzled LDS tile (wave-local: no barrier needed)
#pragma unroll
        for (int nf = 0; nf < 4; ++nf)
#pragma unroll
            for (int j = 0; j < 4; ++j) {
                const int row = fq * 4 + j, col = nf * 16 + fr;
                Ws[wave][row * 64 + (((col >> 3) ^ (row & 7)) << 3) + (fr & 7)] =
                    (bf16)sf[nf][j];
            }
        const bf16* wp = &Ws[wave][fr * 64];
        const bf16x8 wa0 = *(const bf16x8*)&wp[(fq ^ frx) * 8];
        const bf16x8 wa1 = *(const bf16x8*)&wp[((fq + 4) ^ frx) * 8];
        __builtin_amdgcn_s_setprio(1);
#pragma unroll
        for (int f = 0; f < 4; ++f) {
            const bf16* vp = &Vs[(f * 16 + fr) * 64];
            const bf16x8 vb0 = *(const bf16x8*)&vp[(fq ^ frx) * 8];
            const bf16x8 vb1 = *(const bf16x8*)&vp[((fq + 4) ^ frx) * 8];
            o[f] = MFMA16(wa0, vb0, o[f]);
            o[f] = MFMA16(wa1, vb1, o[f]);
        }
        __builtin_amdgcn_s_setprio(0);

        // rotate prefetched scalars (waits on bn arrival = end of compute)
#pragma unroll
        for (int nf = 0; nf < 4; ++nf) {
            mkc[nf] = mkn[nf];
#pragma unroll
            for (int j = 0; j < 4; ++j) bc[nf][j] = bn[nf][j];
        }
        __syncthreads();   // drains K(kt+1) arrival + all Vs/Ws readers
        cur = nxt;
    }

    // epilogue: context (hi/lo) + row stats
#pragma unroll
    for (int j = 0; j < 4; ++j) {
        const float inv = 1.0f / sj[j];
        const int row = n * SL + q0 + wave * 16 + fq * 4 + j;
#pragma unroll
        for (int f = 0; f < 4; ++f) {
            const float v = o[f][j] * inv;
            const size_t off = (size_t)row * ED + h * HD + f * 16 + fr;
            const bf16 hv = (bf16)v;
            ch[off] = hv;
            cl[off] = (bf16)(v - (float)hv);
        }
    }
    if (fr == 0) {
#pragma unroll
        for (int j = 0; j < 4; ++j) {
            const int r = q0 + wave * 16 + fq * 4 + j;
            mrow[((size_t)n * NH + h) * SL + r] = mj[j];
            srow[((size_t)n * NH + h) * SL + r] = sj[j];
        }
    }
}

// ------------------- head-averaged weights v3: LDS-staged, reg accumulator -------------------
__global__ __launch_bounds__(256) void k_avg(
    const bf16* __restrict__ qh, const bf16* __restrict__ kh,
    const float* __restrict__ bias, const int* __restrict__ mask,
    const float* __restrict__ mrow, const float* __restrict__ srow,
    float* __restrict__ avg)
{
    __shared__ __attribute__((aligned(16))) bf16 Qs[2][64 * 64];  // 8KB x2
    __shared__ __attribute__((aligned(16))) bf16 Ks2[2][32 * 64]; // 4KB x2

    const int qt = blockIdx.x, kt = blockIdx.y;
    const int tid = threadIdx.x, wave = tid >> 6, lane = tid & 63;
    const int fr = lane & 15, fq = lane >> 4;
    const int frx = fr & 7;
    const int q0 = qt * 64, k0 = kt * 32;
    const int qr = q0 + wave * 16;
    const f32x4 z4 = {0.f, 0.f, 0.f, 0.f};

    f32x4 acc[4][2];
#pragma unroll
    for (int nn = 0; nn < 4; ++nn)
#pragma unroll
        for (int nf = 0; nf < 2; ++nf) acc[nn][nf] = z4;

    bool mk[4][2];
#pragma unroll
    for (int nn = 0; nn < 4; ++nn)
#pragma unroll
        for (int nf = 0; nf < 2; ++nf)
            mk[nn][nf] = mask[nn * SL + k0 + nf * 16 + fr] != 0;

    auto stage = [&](int hh, int nn2, int b) {
        const bf16* qb = qh + (((size_t)nn2 * NH + hh) * SL + q0) * HD;
        const bf16* kb = kh + (((size_t)nn2 * NH + hh) * SL + k0) * HD;
#pragma unroll
        for (int i = 0; i < 2; ++i) {
            const int li = i * 256 + tid;
            const int r = li >> 3, s = li & 7;
            gl_lds16(qb + (size_t)r * HD + (s ^ (r & 7)) * 8,
                     &Qs[b][(i * 256 + wave * 64) * 8]);
        }
        {
            const int r = tid >> 3, s = tid & 7;
            gl_lds16(kb + (size_t)r * HD + (s ^ (r & 7)) * 8,
                     &Ks2[b][(wave * 64) * 8]);
        }
    };

    stage(0, 0, 0);
    __syncthreads();

    int cur = 0;
#pragma unroll 1
    for (int h = 0; h < NH; ++h) {
        float bfr[2][4];
#pragma unroll
        for (int nf = 0; nf < 2; ++nf)
#pragma unroll
            for (int j = 0; j < 4; ++j)
                bfr[nf][j] = bias[((size_t)h * SL + qr + fq * 4 + j) * SL + k0 + nf * 16 + fr];

#pragma unroll
        for (int nn = 0; nn < 4; ++nn) {
            const int ih = h * 4 + nn;
            const int nxt = cur ^ 1;
            if (ih < 63) stage((ih + 1) >> 2, (ih + 1) & 3, nxt);

            const size_t sidx = ((size_t)nn * NH + h) * SL + qr + fq * 4;
            const f32x4 mv = *(const f32x4*)(mrow + sidx);
            const f32x4 sv = *(const f32x4*)(srow + sidx);
            float t2[2][4];
#pragma unroll
        for (int j = 0; j < 4; ++j) {
                const float lg = __logf(16.0f * sv[j]);
#pragma unroll
                for (int nf = 0; nf < 2; ++nf)
                    t2[nf][j] = mk[nn][nf] ? -1e30f : (bfr[nf][j] - mv[j] - lg);
            }

            const bf16* qp = &Qs[cur][(wave * 16 + fr) * 64];
            const bf16x8 qf0 = *(const bf16x8*)&qp[(fq ^ frx) * 8];
            const bf16x8 qf1 = *(const bf16x8*)&qp[((fq + 4) ^ frx) * 8];
#pragma unroll
            for (int nf = 0; nf < 2; ++nf) {
                const bf16* kp = &Ks2[cur][(nf * 16 + fr) * 64];
                const bf16x8 b0 = *(const bf16x8*)&kp[(fq ^ frx) * 8];
                const bf16x8 b1 = *(const bf16x8*)&kp[((fq + 4) ^ frx) * 8];
                f32x4 a = z4;
                a = MFMA16(qf0, b0, a);
                a = MFMA16(qf1, b1, a);
#pragma unroll
                for (int j = 0; j < 4; ++j)
                    acc[nn][nf][j] += __expf(a[j] + t2[nf][j]);
            }
            __syncthreads();
            cur = nxt;
        }
    }

#pragma unroll
    for (int nn = 0; nn < 4; ++nn)
#pragma unroll
        for (int j = 0; j < 4; ++j) {
            const size_t rowoff = ((size_t)nn * SL + qr + fq * 4 + j) * SL;
#pragma unroll
            for (int nf = 0; nf < 2; ++nf)
                avg[rowoff + k0 + nf * 16 + fr] = acc[nn][nf][j];
        }
}

// ------------------- launcher -------------------
extern "C" void kernel_launch(void* const* d_in, const int* in_sizes, int n_in,
                              void* d_out, int out_size, void* d_ws, size_t ws_size,
                              hipStream_t stream)
{
    (void)in_sizes; (void)n_in; (void)out_size; (void)ws_size;
    const float* query = (const float*)d_in[0];
    const float* bias  = (const float*)d_in[1];
    const int* mask = (const int*)d_in[2];
    const float* Wq = (const float*)d_in[3];
    const float* bq = (const float*)d_in[4];
    const float* Wk = (const float*)d_in[5];
    const float* bk = (const float*)d_in[6];
    const float* Wv = (const float*)d_in[7];
    const float* bv = (const float*)d_in[8];
    const float* Wo = (const float*)d_in[9];
    const float* bo = (const float*)d_in[10];
    float* out0 = (float*)d_out;                      // [N,L,E]
    float* out1 = out0 + (size_t)MR * ED;             // [N,L,L]

    char* p = (char*)d_ws;
    auto carve = [&](size_t bytes) {
        char* r = p;
        p += (bytes + 255) & ~(size_t)255;
        return r;
    };
    const size_t QKVB = (size_t)NB * NH * SL * HD * 2;   // 16.78 MB
    bf16* xh = (bf16*)carve((size_t)MR * ED * 2);
    bf16* xl = (bf16*)carve((size_t)MR * ED * 2);
    bf16* wh = (bf16*)carve((size_t)4 * ED * ED * 2);
    bf16* wl = (bf16*)carve((size_t)4 * ED * ED * 2);
    bf16* qh = (bf16*)carve(QKVB);
    bf16* kh = (bf16*)carve(QKVB);
    bf16* vh = (bf16*)carve(QKVB);
    float* mrow = (float*)carve((size_t)NB * NH * SL * 4);
    float* srow = (float*)carve((size_t)NB * NH * SL * 4);
    bf16* ch = (bf16*)carve((size_t)MR * ED * 2);
    bf16* cl = (bf16*)carve((size_t)MR * ED * 2);

    // 1. split inputs to hi/lo bf16
    {
        const int n4 = MR * ED / 4;
        k_split<<<(n4 + 255) / 256, 256, 0, stream>>>(query, xh, xl, n4);
        const int w4 = ED * ED / 4;
        const float* Ws4[4] = {Wq, Wk, Wv, Wo};
        for (int i = 0; i < 4; ++i)
            k_split<<<(w4 + 255) / 256, 256, 0, stream>>>(
                Ws4[i], wh + (size_t)i * ED * ED, wl + (size_t)i * ED * ED, w4);
    }
    // 2. QKV projections
    k_qkv_gemm<<<dim3(MR / 128, ED / 128, 3), 256, 0, stream>>>(
        xh, xl, wh, wl, bq, bk, bv, qh, kh, vh);
    // 3. flash attention + row stats + context
    k_flash<<<dim3(2048), 256, 0, stream>>>(
        qh, kh, vh, bias, mask, ch, cl, mrow, srow);
    // 4. head-averaged attention weights
    k_avg<<<dim3(SL / 64, SL / 32), 256, 0, stream>>>(
        qh, kh, bias, mask, mrow, srow, out1);
    // 5. output projection
    k_out_gemm<<<dim3(MR / 128, ED / 128), 256, 0, stream>>>(
        ch, cl, wh + (size_t)3 * ED * ED, wl + (size_t)3 * ED * ED, bo, out0);
}

// Round 11
// 777.399 us; speedup vs baseline: 2.1311x; 1.0066x over previous
//
#include <hip/hip_runtime.h>
#include <stdint.h>

typedef __bf16 bf16;
typedef __bf16 bf16x4 __attribute__((ext_vector_type(4)));
typedef __bf16 bf16x8 __attribute__((ext_vector_type(8)));
typedef float f32x4 __attribute__((ext_vector_type(4)));

#define MFMA16(a, b, c) __builtin_amdgcn_mfma_f32_16x16x32_bf16((a), (b), (c), 0, 0, 0)

static constexpr int NB = 4;      // batch
static constexpr int NH = 16;     // heads
static constexpr int SL = 2048;   // seq len
static constexpr int HD = 64;     // head dim
static constexpr int ED = 1024;   // embed
static constexpr int MR = NB * SL; // 8192 rows

__device__ __forceinline__ void gl_lds16(const void* g, void* l) {
    __builtin_amdgcn_global_load_lds(
        (const __attribute__((address_space(1))) unsigned int*)g,
        (__attribute__((address_space(3))) unsigned int*)l, 16, 0, 0);
}

// ------------------- f32 -> bf16 hi/lo split -------------------
__global__ void k_split(const float* __restrict__ src, bf16* __restrict__ hi,
                        bf16* __restrict__ lo, int n4) {
    int i = blockIdx.x * blockDim.x + threadIdx.x;
    if (i >= n4) return;
    const float4 v = ((const float4*)src)[i];
    float vv[4] = {v.x, v.y, v.z, v.w};
    bf16x4 hv, lv;
#pragma unroll
    for (int e = 0; e < 4; ++e) {
        bf16 h = (bf16)vv[e];
        hv[e] = h;
        lv[e] = (bf16)(vv[e] - (float)h);
    }
    ((bf16x4*)hi)[i] = hv;
    ((bf16x4*)lo)[i] = lv;
}

// ------------------- QKV projection GEMM (hi/lo inputs, bf16 outputs) -------------------
__global__ __launch_bounds__(256) void k_qkv_gemm(
    const bf16* __restrict__ xh, const bf16* __restrict__ xl,
    const bf16* __restrict__ wh, const bf16* __restrict__ wl,
    const float* __restrict__ bq, const float* __restrict__ bk,
    const float* __restrict__ bv,
    bf16* __restrict__ qh, bf16* __restrict__ kh, bf16* __restrict__ vh)
{
    __shared__ __attribute__((aligned(16))) bf16 As[2][128 * 32];
    __shared__ __attribute__((aligned(16))) bf16 Bs[2][128 * 32];

    const int z  = blockIdx.z;           // 0=q,1=k,2=v
    const int m0 = blockIdx.x * 128;
    const int n0 = blockIdx.y * 128;
    const int tid = threadIdx.x, wave = tid >> 6, lane = tid & 63;
    const int wr = wave >> 1, wc = wave & 1;
    const int fr = lane & 15, fq = lane >> 4;
    const bf16* Wh = wh + (size_t)z * ED * ED;
    const bf16* Wl = wl + (size_t)z * ED * ED;

    const f32x4 z4 = {0.f, 0.f, 0.f, 0.f};
    f32x4 acc[4][4];
#pragma unroll
    for (int i = 0; i < 4; ++i)
#pragma unroll
        for (int j = 0; j < 4; ++j) acc[i][j] = z4;

#pragma unroll 1
    for (int kk = 0; kk < ED; kk += 32) {
#pragma unroll
        for (int r = 0; r < 2; ++r) {
            const int chunk = r * 256 + tid;
            const int row = chunk >> 2, c8 = (chunk & 3) * 8;
            const size_t ax = (size_t)(m0 + row) * ED + kk + c8;
            const size_t bx = (size_t)(n0 + row) * ED + kk + c8;
            const int db = (r * 256 + wave * 64) * 8;   // wave-uniform LDS base
            gl_lds16(xh + ax, &As[0][db]);
            gl_lds16(xl + ax, &As[1][db]);
            gl_lds16(Wh + bx, &Bs[0][db]);
            gl_lds16(Wl + bx, &Bs[1][db]);
        }
        __syncthreads();
        bf16x8 af[4][2], bfg[4][2];
#pragma unroll
        for (int i = 0; i < 4; ++i) {
            const int arow = wr * 64 + i * 16 + fr;
            af[i][0] = *(const bf16x8*)&As[0][arow * 32 + fq * 8];
            af[i][1] = *(const bf16x8*)&As[1][arow * 32 + fq * 8];
            const int brow = wc * 64 + i * 16 + fr;
            bfg[i][0] = *(const bf16x8*)&Bs[0][brow * 32 + fq * 8];
            bfg[i][1] = *(const bf16x8*)&Bs[1][brow * 32 + fq * 8];
        }
#pragma unroll
        for (int mi = 0; mi < 4; ++mi)
#pragma unroll
            for (int ni = 0; ni < 4; ++ni) {
                acc[mi][ni] = MFMA16(af[mi][0], bfg[ni][0], acc[mi][ni]);
                acc[mi][ni] = MFMA16(af[mi][0], bfg[ni][1], acc[mi][ni]);
                acc[mi][ni] = MFMA16(af[mi][1], bfg[ni][0], acc[mi][ni]);
            }
        __syncthreads();
    }

    const float* bias = (z == 0) ? bq : (z == 1) ? bk : bv;
#pragma unroll
    for (int mi = 0; mi < 4; ++mi) {
#pragma unroll
        for (int ni = 0; ni < 4; ++ni) {
            const int col = n0 + wc * 64 + ni * 16 + fr;
            const int hh = col >> 6, dd = col & 63;
#pragma unroll
            for (int j = 0; j < 4; ++j) {
                const int row = m0 + wr * 64 + mi * 16 + fq * 4 + j;
                float v = acc[mi][ni][j] + bias[col];
                const int nb = row >> 11, li = row & (SL - 1);
                const size_t off = (((size_t)nb * NH + hh) * SL + li) * HD + dd;
                if (z == 0) {
                    qh[off] = (bf16)(v * 0.125f);      // head_dim^-0.5
                } else if (z == 1) {
                    kh[off] = (bf16)v;
                } else {
                    vh[off] = (bf16)v;
                }
            }
        }
    }
}

// ------------------- output projection GEMM (hi/lo) -------------------
__global__ __launch_bounds__(256) void k_out_gemm(
    const bf16* __restrict__ ah, const bf16* __restrict__ al,
    const bf16* __restrict__ wh, const bf16* __restrict__ wl,
    const float* __restrict__ bo, float* __restrict__ out)
{
    __shared__ __attribute__((aligned(16))) bf16 As[2][128 * 32];
    __shared__ __attribute__((aligned(16))) bf16 Bs[2][128 * 32];

    const int m0 = blockIdx.x * 128;
    const int n0 = blockIdx.y * 128;
    const int tid = threadIdx.x, wave = tid >> 6, lane = tid & 63;
    const int wr = wave >> 1, wc = wave & 1;
    const int fr = lane & 15, fq = lane >> 4;

    const f32x4 z4 = {0.f, 0.f, 0.f, 0.f};
    f32x4 acc[4][4];
#pragma unroll
    for (int i = 0; i < 4; ++i)
#pragma unroll
        for (int j = 0; j < 4; ++j) acc[i][j] = z4;

#pragma unroll 1
    for (int kk = 0; kk < ED; kk += 32) {
#pragma unroll
        for (int r = 0; r < 2; ++r) {
            const int chunk = r * 256 + tid;
            const int row = chunk >> 2, c8 = (chunk & 3) * 8;
            const size_t ax = (size_t)(m0 + row) * ED + kk + c8;
            const size_t bx = (size_t)(n0 + row) * ED + kk + c8;
            const int db = (r * 256 + wave * 64) * 8;
            gl_lds16(ah + ax, &As[0][db]);
            gl_lds16(al + ax, &As[1][db]);
            gl_lds16(wh + bx, &Bs[0][db]);
            gl_lds16(wl + bx, &Bs[1][db]);
        }
        __syncthreads();
        bf16x8 af[4][2], bfg[4][2];
#pragma unroll
        for (int i = 0; i < 4; ++i) {
            const int arow = wr * 64 + i * 16 + fr;
            af[i][0] = *(const bf16x8*)&As[0][arow * 32 + fq * 8];
            af[i][1] = *(const bf16x8*)&As[1][arow * 32 + fq * 8];
            const int brow = wc * 64 + i * 16 + fr;
            bfg[i][0] = *(const bf16x8*)&Bs[0][brow * 32 + fq * 8];
            bfg[i][1] = *(const bf16x8*)&Bs[1][brow * 32 + fq * 8];
        }
#pragma unroll
        for (int mi = 0; mi < 4; ++mi)
#pragma unroll
            for (int ni = 0; ni < 4; ++ni) {
                acc[mi][ni] = MFMA16(af[mi][0], bfg[ni][0], acc[mi][ni]);
                acc[mi][ni] = MFMA16(af[mi][0], bfg[ni][1], acc[mi][ni]);
                acc[mi][ni] = MFMA16(af[mi][1], bfg[ni][0], acc[mi][ni]);
            }
        __syncthreads();
    }

#pragma unroll
    for (int mi = 0; mi < 4; ++mi)
#pragma unroll
        for (int ni = 0; ni < 4; ++ni) {
            const int col = n0 + wc * 64 + ni * 16 + fr;
#pragma unroll
            for (int j = 0; j < 4; ++j) {
                const int row = m0 + wr * 64 + mi * 16 + fq * 4 + j;
                out[(size_t)row * ED + col] = acc[mi][ni][j] + bo[col];
            }
        }
}

// ------------------- flash attention v5: coalesced V loads -------------------
// V loaded coalesced (thread: key=tid>>3, d-chunk=(tid&7)*8; 1KB contiguous per
// wave-instr) and written transposed at swizzled slots with d-rotation:
// chunk(d,key) = (key>>3) ^ (d&7) ^ ((d>>3)&7). Ks double-buffered as v4.
__global__ __launch_bounds__(256) void k_flash(
    const bf16* __restrict__ qh, const bf16* __restrict__ kh,
    const bf16* __restrict__ vh,
    const float* __restrict__ bias, const int* __restrict__ mask,
    bf16* __restrict__ ch, bf16* __restrict__ cl,
    float* __restrict__ mrow, float* __restrict__ srow)
{
    __shared__ __attribute__((aligned(16))) bf16 Ks[2][64 * 64];  // [key][d] swz, dbuf
    __shared__ __attribute__((aligned(16))) bf16 Vs[64 * 64];     // [d][key] swz+rot
    __shared__ __attribute__((aligned(16))) bf16 Ws[4][16 * 64];  // per-wave P, swz

    // block map: xcd gets 2 heads; within: qt sweeps, n fastest (bias L2 reuse)
    const int bid = blockIdx.x;
    const int xcd = bid & 7, local = bid >> 3;
    const int h = xcd * 2 + (local >> 7);
    const int rem = local & 127;
    const int qt = rem >> 2, n = rem & 3;

    const int tid = threadIdx.x, wave = tid >> 6, lane = tid & 63;
    const int fr = lane & 15, fq = lane >> 4;
    const int frx = fr & 7;
    const int q0 = qt * 64;
    const size_t hoff = ((size_t)n * NH + h) * SL * HD;
    const f32x4 z4 = {0.f, 0.f, 0.f, 0.f};

    bf16x8 qf0, qf1;
    {
        const size_t qb = hoff + (size_t)(q0 + wave * 16 + fr) * HD + fq * 8;
        qf0 = *(const bf16x8*)(qh + qb);
        qf1 = *(const bf16x8*)(qh + qb + 32);
    }

    f32x4 o[4];
#pragma unroll
    for (int f = 0; f < 4; ++f) o[f] = z4;
    float mj[4] = {-3e38f, -3e38f, -3e38f, -3e38f};
    float sj[4] = {0.f, 0.f, 0.f, 0.f};
    size_t brow[4];
#pragma unroll
    for (int j = 0; j < 4; ++j)
        brow[j] = ((size_t)h * SL + q0 + wave * 16 + fq * 4 + j) * SL;
    const int* mkb = mask + n * SL;

    // V coalesced-load mapping: key = vk (+0 / +32), d-chunk start = vd0
    const int vk = tid >> 3;            // 0..31
    const int vd0 = (tid & 7) * 8;      // 0..56 ; d>>3 == tid&7 for this chunk
    const int vrot = tid & 7;           // (d>>3)&7 for all 8 elems of the chunk
    const int k3A = vk >> 3, k3B = 4 + (vk >> 3), k7 = vk & 7;

    // ---- prologue: issue K(0)->Ks[0]; V(0)/bias(0)/mask(0) -> regs ----
#pragma unroll
    for (int i = 0; i < 2; ++i) {
        const int li = i * 256 + tid;
        const int r = li >> 3, s = li & 7;
        gl_lds16(kh + hoff + (size_t)r * HD + (s ^ (r & 7)) * 8,
                 &Ks[0][(i * 256 + wave * 64) * 8]);
    }
    bf16x8 vrA = *(const bf16x8*)(vh + hoff + (size_t)vk * HD + vd0);
    bf16x8 vrB = *(const bf16x8*)(vh + hoff + (size_t)(32 + vk) * HD + vd0);
    float bc[4][4];
    int mkc[4];
#pragma unroll
    for (int nf = 0; nf < 4; ++nf) {
        mkc[nf] = mkb[nf * 16 + fr];
#pragma unroll
        for (int j = 0; j < 4; ++j)
            bc[nf][j] = bias[brow[j] + nf * 16 + fr];
    }
    __syncthreads();   // drains K(0) (one-time exposed latency)

    int cur = 0;
#pragma unroll 1
    for (int kt = 0; kt < 32; ++kt) {
        const int nxt = cur ^ 1;
        const int kp1 = (kt < 31) ? kt + 1 : 31;

        // ---- A: Vs <- vrA/vrB (V(kt)); transposed, swizzled+rotated ----
#pragma unroll
        for (int e = 0; e < 8; ++e) {
            const int d = vd0 + e;
            Vs[d * 64 + ((k3A ^ e ^ vrot) << 3) + k7] = vrA[e];
            Vs[d * 64 + ((k3B ^ e ^ vrot) << 3) + k7] = vrB[e];
        }
        __syncthreads();   // Vs visible (lgkm only; no vmem outstanding here)

        // ---- B: issue next-tile prefetches (covered by phase C compute) ----
#pragma unroll
        for (int i = 0; i < 2; ++i) {
            const int li = i * 256 + tid;
            const int r = li >> 3, s = li & 7;
            gl_lds16(kh + hoff + (size_t)(kp1 * 64 + r) * HD + (s ^ (r & 7)) * 8,
                     &Ks[nxt][(i * 256 + wave * 64) * 8]);
        }
        vrA = *(const bf16x8*)(vh + hoff + (size_t)(kp1 * 64 + vk) * HD + vd0);
        vrB = *(const bf16x8*)(vh + hoff + (size_t)(kp1 * 64 + 32 + vk) * HD + vd0);
        float bn[4][4];
        int mkn[4];
#pragma unroll
        for (int nf = 0; nf < 4; ++nf) {
            mkn[nf] = mkb[kp1 * 64 + nf * 16 + fr];
#pragma unroll
            for (int j = 0; j < 4; ++j)
                bn[nf][j] = bias[brow[j] + kp1 * 64 + nf * 16 + fr];
        }

        // ---- C: compute QK^T on Ks[cur] ----
        f32x4 sf[4];
        __builtin_amdgcn_s_setprio(1);
#pragma unroll
        for (int nf = 0; nf < 4; ++nf) {
            const bf16* kp = &Ks[cur][(nf * 16 + fr) * 64];
            const bf16x8 b0 = *(const bf16x8*)&kp[(fq ^ frx) * 8];
            const bf16x8 b1 = *(const bf16x8*)&kp[((fq + 4) ^ frx) * 8];
            f32x4 a = z4;
            a = MFMA16(qf0, b0, a);
            a = MFMA16(qf1, b1, a);
            sf[nf] = a;
        }
        __builtin_amdgcn_s_setprio(0);

        // bias + mask (current tile, prefetched last iteration)
#pragma unroll
        for (int nf = 0; nf < 4; ++nf) {
            const bool mk = mkc[nf] != 0;
#pragma unroll
            for (int j = 0; j < 4; ++j) {
                float s = sf[nf][j] + bc[nf][j];
                sf[nf][j] = mk ? -1e30f : s;
            }
        }
        // online softmax (rows wave-local; 16-lane butterfly)
        float tmax[4];
#pragma unroll
        for (int j = 0; j < 4; ++j)
            tmax[j] = fmaxf(fmaxf(sf[0][j], sf[1][j]), fmaxf(sf[2][j], sf[3][j]));
#pragma unroll
        for (int d = 1; d < 16; d <<= 1)
#pragma unroll
            for (int j = 0; j < 4; ++j)
                tmax[j] = fmaxf(tmax[j], __shfl_xor(tmax[j], d));
        float scale[4];
#pragma unroll
        for (int j = 0; j < 4; ++j) {
            const float mn = fmaxf(mj[j], tmax[j]);
            scale[j] = __expf(mj[j] - mn);
            mj[j] = mn;
        }
        float rs[4] = {0.f, 0.f, 0.f, 0.f};
#pragma unroll
        for (int nf = 0; nf < 4; ++nf)
#pragma unroll
            for (int j = 0; j < 4; ++j) {
                const float w = __expf(sf[nf][j] - mj[j]);
                sf[nf][j] = w;
                rs[j] += w;
            }
#pragma unroll
        for (int d = 1; d < 16; d <<= 1)
#pragma unroll
            for (int j = 0; j < 4; ++j)
                rs[j] += __shfl_xor(rs[j], d);
#pragma unroll
        for (int j = 0; j < 4; ++j) sj[j] = sj[j] * scale[j] + rs[j];
#pragma unroll
        for (int f = 0; f < 4; ++f)
#pragma unroll
            for (int j = 0; j < 4; ++j) o[f][j] *= scale[j];

        // P -> per-wave swizzled LDS tile (wave-local: no barrier needed)
#pragma unroll
        for (int nf = 0; nf < 4; ++nf)
#pragma unroll
            for (int j = 0; j < 4; ++j) {
                const int row = fq * 4 + j, col = nf * 16 + fr;
                Ws[wave][row * 64 + (((col >> 3) ^ (row & 7)) << 3) + (fr & 7)] =
                    (bf16)sf[nf][j];
            }
        const bf16* wp = &Ws[wave][fr * 64];
        const bf16x8 wa0 = *(const bf16x8*)&wp[(fq ^ frx) * 8];
        const bf16x8 wa1 = *(const bf16x8*)&wp[((fq + 4) ^ frx) * 8];
        __builtin_amdgcn_s_setprio(1);
#pragma unroll
        for (int f = 0; f < 4; ++f) {
            const int rot = (f * 2 + (fr >> 3)) & 7;   // (d>>3)&7 for d = f*16+fr
            const bf16* vp = &Vs[(f * 16 + fr) * 64];
            const bf16x8 vb0 = *(const bf16x8*)&vp[((fq ^ frx ^ rot) & 7) * 8];
            const bf16x8 vb1 = *(const bf16x8*)&vp[(((fq + 4) ^ frx ^ rot) & 7) * 8];
            o[f] = MFMA16(wa0, vb0, o[f]);
            o[f] = MFMA16(wa1, vb1, o[f]);
        }
        __builtin_amdgcn_s_setprio(0);

        // rotate prefetched scalars (waits on bn arrival = end of compute)
#pragma unroll
        for (int nf = 0; nf < 4; ++nf) {
            mkc[nf] = mkn[nf];
#pragma unroll
            for (int j = 0; j < 4; ++j) bc[nf][j] = bn[nf][j];
        }
        __syncthreads();   // drains K(kt+1) arrival + all Vs/Ws readers
        cur = nxt;
    }

    // epilogue: context (hi/lo) + row stats
#pragma unroll
    for (int j = 0; j < 4; ++j) {
        const float inv = 1.0f / sj[j];
        const int row = n * SL + q0 + wave * 16 + fq * 4 + j;
#pragma unroll
        for (int f = 0; f < 4; ++f) {
            const float v = o[f][j] * inv;
            const size_t off = (size_t)row * ED + h * HD + f * 16 + fr;
            const bf16 hv = (bf16)v;
            ch[off] = hv;
            cl[off] = (bf16)(v - (float)hv);
        }
    }
    if (fr == 0) {
#pragma unroll
        for (int j = 0; j < 4; ++j) {
            const int r = q0 + wave * 16 + fq * 4 + j;
            mrow[((size_t)n * NH + h) * SL + r] = mj[j];
            srow[((size_t)n * NH + h) * SL + r] = sj[j];
        }
    }
}

// ------------------- head-averaged weights v3: LDS-staged, reg accumulator -------------------
__global__ __launch_bounds__(256) void k_avg(
    const bf16* __restrict__ qh, const bf16* __restrict__ kh,
    const float* __restrict__ bias, const int* __restrict__ mask,
    const float* __restrict__ mrow, const float* __restrict__ srow,
    float* __restrict__ avg)
{
    __shared__ __attribute__((aligned(16))) bf16 Qs[2][64 * 64];  // 8KB x2
    __shared__ __attribute__((aligned(16))) bf16 Ks2[2][32 * 64]; // 4KB x2

    const int qt = blockIdx.x, kt = blockIdx.y;
    const int tid = threadIdx.x, wave = tid >> 6, lane = tid & 63;
    const int fr = lane & 15, fq = lane >> 4;
    const int frx = fr & 7;
    const int q0 = qt * 64, k0 = kt * 32;
    const int qr = q0 + wave * 16;
    const f32x4 z4 = {0.f, 0.f, 0.f, 0.f};

    f32x4 acc[4][2];
#pragma unroll
    for (int nn = 0; nn < 4; ++nn)
#pragma unroll
        for (int nf = 0; nf < 2; ++nf) acc[nn][nf] = z4;

    bool mk[4][2];
#pragma unroll
    for (int nn = 0; nn < 4; ++nn)
#pragma unroll
        for (int nf = 0; nf < 2; ++nf)
            mk[nn][nf] = mask[nn * SL + k0 + nf * 16 + fr] != 0;

    auto stage = [&](int hh, int nn2, int b) {
        const bf16* qb = qh + (((size_t)nn2 * NH + hh) * SL + q0) * HD;
        const bf16* kb = kh + (((size_t)nn2 * NH + hh) * SL + k0) * HD;
#pragma unroll
        for (int i = 0; i < 2; ++i) {
            const int li = i * 256 + tid;
            const int r = li >> 3, s = li & 7;
            gl_lds16(qb + (size_t)r * HD + (s ^ (r & 7)) * 8,
                     &Qs[b][(i * 256 + wave * 64) * 8]);
        }
        {
            const int r = tid >> 3, s = tid & 7;
            gl_lds16(kb + (size_t)r * HD + (s ^ (r & 7)) * 8,
                     &Ks2[b][(wave * 64) * 8]);
        }
    };

    stage(0, 0, 0);
    __syncthreads();

    int cur = 0;
#pragma unroll 1
    for (int h = 0; h < NH; ++h) {
        float bfr[2][4];
#pragma unroll
        for (int nf = 0; nf < 2; ++nf)
#pragma unroll
            for (int j = 0; j < 4; ++j)
                bfr[nf][j] = bias[((size_t)h * SL + qr + fq * 4 + j) * SL + k0 + nf * 16 + fr];

#pragma unroll
        for (int nn = 0; nn < 4; ++nn) {
            const int ih = h * 4 + nn;
            const int nxt = cur ^ 1;
            if (ih < 63) stage((ih + 1) >> 2, (ih + 1) & 3, nxt);

            const size_t sidx = ((size_t)nn * NH + h) * SL + qr + fq * 4;
            const f32x4 mv = *(const f32x4*)(mrow + sidx);
            const f32x4 sv = *(const f32x4*)(srow + sidx);
            float t2[2][4];
#pragma unroll
        for (int j = 0; j < 4; ++j) {
                const float lg = __logf(16.0f * sv[j]);
#pragma unroll
                for (int nf = 0; nf < 2; ++nf)
                    t2[nf][j] = mk[nn][nf] ? -1e30f : (bfr[nf][j] - mv[j] - lg);
            }

            const bf16* qp = &Qs[cur][(wave * 16 + fr) * 64];
            const bf16x8 qf0 = *(const bf16x8*)&qp[(fq ^ frx) * 8];
            const bf16x8 qf1 = *(const bf16x8*)&qp[((fq + 4) ^ frx) * 8];
#pragma unroll
            for (int nf = 0; nf < 2; ++nf) {
                const bf16* kp = &Ks2[cur][(nf * 16 + fr) * 64];
                const bf16x8 b0 = *(const bf16x8*)&kp[(fq ^ frx) * 8];
                const bf16x8 b1 = *(const bf16x8*)&kp[((fq + 4) ^ frx) * 8];
                f32x4 a = z4;
                a = MFMA16(qf0, b0, a);
                a = MFMA16(qf1, b1, a);
#pragma unroll
                for (int j = 0; j < 4; ++j)
                    acc[nn][nf][j] += __expf(a[j] + t2[nf][j]);
            }
            __syncthreads();
            cur = nxt;
        }
    }

#pragma unroll
    for (int nn = 0; nn < 4; ++nn)
#pragma unroll
        for (int j = 0; j < 4; ++j) {
            const size_t rowoff = ((size_t)nn * SL + qr + fq * 4 + j) * SL;
#pragma unroll
            for (int nf = 0; nf < 2; ++nf)
                avg[rowoff + k0 + nf * 16 + fr] = acc[nn][nf][j];
        }
}

// ------------------- launcher -------------------
extern "C" void kernel_launch(void* const* d_in, const int* in_sizes, int n_in,
                              void* d_out, int out_size, void* d_ws, size_t ws_size,
                              hipStream_t stream)
{
    (void)in_sizes; (void)n_in; (void)out_size; (void)ws_size;
    const float* query = (const float*)d_in[0];
    const float* bias  = (const float*)d_in[1];
    const int* mask = (const int*)d_in[2];
    const float* Wq = (const float*)d_in[3];
    const float* bq = (const float*)d_in[4];
    const float* Wk = (const float*)d_in[5];
    const float* bk = (const float*)d_in[6];
    const float* Wv = (const float*)d_in[7];
    const float* bv = (const float*)d_in[8];
    const float* Wo = (const float*)d_in[9];
    const float* bo = (const float*)d_in[10];
    float* out0 = (float*)d_out;                      // [N,L,E]
    float* out1 = out0 + (size_t)MR * ED;             // [N,L,L]

    char* p = (char*)d_ws;
    auto carve = [&](size_t bytes) {
        char* r = p;
        p += (bytes + 255) & ~(size_t)255;
        return r;
    };
    const size_t QKVB = (size_t)NB * NH * SL * HD * 2;   // 16.78 MB
    bf16* xh = (bf16*)carve((size_t)MR * ED * 2);
    bf16* xl = (bf16*)carve((size_t)MR * ED * 2);
    bf16* wh = (bf16*)carve((size_t)4 * ED * ED * 2);
    bf16* wl = (bf16*)carve((size_t)4 * ED * ED * 2);
    bf16* qh = (bf16*)carve(QKVB);
    bf16* kh = (bf16*)carve(QKVB);
    bf16* vh = (bf16*)carve(QKVB);
    float* mrow = (float*)carve((size_t)NB * NH * SL * 4);
    float* srow = (float*)carve((size_t)NB * NH * SL * 4);
    bf16* ch = (bf16*)carve((size_t)MR * ED * 2);
    bf16* cl = (bf16*)carve((size_t)MR * ED * 2);

    // 1. split inputs to hi/lo bf16
    {
        const int n4 = MR * ED / 4;
        k_split<<<(n4 + 255) / 256, 256, 0, stream>>>(query, xh, xl, n4);
        const int w4 = ED * ED / 4;
        const float* Ws4[4] = {Wq, Wk, Wv, Wo};
        for (int i = 0; i < 4; ++i)
            k_split<<<(w4 + 255) / 256, 256, 0, stream>>>(
                Ws4[i], wh + (size_t)i * ED * ED, wl + (size_t)i * ED * ED, w4);
    }
    // 2. QKV projections
    k_qkv_gemm<<<dim3(MR / 128, ED / 128, 3), 256, 0, stream>>>(
        xh, xl, wh, wl, bq, bk, bv, qh, kh, vh);
    // 3. flash attention + row stats + context
    k_flash<<<dim3(2048), 256, 0, stream>>>(
        qh, kh, vh, bias, mask, ch, cl, mrow, srow);
    // 4. head-averaged attention weights
    k_avg<<<dim3(SL / 64, SL / 32), 256, 0, stream>>>(
        qh, kh, bias, mask, mrow, srow, out1);
    // 5. output projection
    k_out_gemm<<<dim3(MR / 128, ED / 128), 256, 0, stream>>>(
        ch, cl, wh + (size_t)3 * ED * ED, wl + (size_t)3 * ED * ED, bo, out0);
}

// Round 12
// 714.775 us; speedup vs baseline: 2.3178x; 1.0876x over previous
//
#include <hip/hip_runtime.h>
#include <stdint.h>

typedef __bf16 bf16;
typedef __bf16 bf16x4 __attribute__((ext_vector_type(4)));
typedef __bf16 bf16x8 __attribute__((ext_vector_type(8)));
typedef float f32x4 __attribute__((ext_vector_type(4)));

#define MFMA16(a, b, c) __builtin_amdgcn_mfma_f32_16x16x32_bf16((a), (b), (c), 0, 0, 0)

static constexpr int NB = 4;      // batch
static constexpr int NH = 16;     // heads
static constexpr int SL = 2048;   // seq len
static constexpr int HD = 64;     // head dim
static constexpr int ED = 1024;   // embed
static constexpr int MR = NB * SL; // 8192 rows

__device__ __forceinline__ void gl_lds16(const void* g, void* l) {
    __builtin_amdgcn_global_load_lds(
        (const __attribute__((address_space(1))) unsigned int*)g,
        (__attribute__((address_space(3))) unsigned int*)l, 16, 0, 0);
}

// ------------------- f32 -> bf16 hi/lo split -------------------
__global__ void k_split(const float* __restrict__ src, bf16* __restrict__ hi,
                        bf16* __restrict__ lo, int n4) {
    int i = blockIdx.x * blockDim.x + threadIdx.x;
    if (i >= n4) return;
    const float4 v = ((const float4*)src)[i];
    float vv[4] = {v.x, v.y, v.z, v.w};
    bf16x4 hv, lv;
#pragma unroll
    for (int e = 0; e < 4; ++e) {
        bf16 h = (bf16)vv[e];
        hv[e] = h;
        lv[e] = (bf16)(vv[e] - (float)h);
    }
    ((bf16x4*)hi)[i] = hv;
    ((bf16x4*)lo)[i] = lv;
}

// ------------------- QKV projection GEMM (hi/lo inputs, bf16 outputs) -------------------
__global__ __launch_bounds__(256) void k_qkv_gemm(
    const bf16* __restrict__ xh, const bf16* __restrict__ xl,
    const bf16* __restrict__ wh, const bf16* __restrict__ wl,
    const float* __restrict__ bq, const float* __restrict__ bk,
    const float* __restrict__ bv,
    bf16* __restrict__ qh, bf16* __restrict__ kh, bf16* __restrict__ vh)
{
    __shared__ __attribute__((aligned(16))) bf16 As[2][128 * 32];
    __shared__ __attribute__((aligned(16))) bf16 Bs[2][128 * 32];

    const int z  = blockIdx.z;           // 0=q,1=k,2=v
    const int m0 = blockIdx.x * 128;
    const int n0 = blockIdx.y * 128;
    const int tid = threadIdx.x, wave = tid >> 6, lane = tid & 63;
    const int wr = wave >> 1, wc = wave & 1;
    const int fr = lane & 15, fq = lane >> 4;
    const bf16* Wh = wh + (size_t)z * ED * ED;
    const bf16* Wl = wl + (size_t)z * ED * ED;

    const f32x4 z4 = {0.f, 0.f, 0.f, 0.f};
    f32x4 acc[4][4];
#pragma unroll
    for (int i = 0; i < 4; ++i)
#pragma unroll
        for (int j = 0; j < 4; ++j) acc[i][j] = z4;

#pragma unroll 1
    for (int kk = 0; kk < ED; kk += 32) {
#pragma unroll
        for (int r = 0; r < 2; ++r) {
            const int chunk = r * 256 + tid;
            const int row = chunk >> 2, c8 = (chunk & 3) * 8;
            const size_t ax = (size_t)(m0 + row) * ED + kk + c8;
            const size_t bx = (size_t)(n0 + row) * ED + kk + c8;
            const int db = (r * 256 + wave * 64) * 8;   // wave-uniform LDS base
            gl_lds16(xh + ax, &As[0][db]);
            gl_lds16(xl + ax, &As[1][db]);
            gl_lds16(Wh + bx, &Bs[0][db]);
            gl_lds16(Wl + bx, &Bs[1][db]);
        }
        __syncthreads();
        bf16x8 af[4][2], bfg[4][2];
#pragma unroll
        for (int i = 0; i < 4; ++i) {
            const int arow = wr * 64 + i * 16 + fr;
            af[i][0] = *(const bf16x8*)&As[0][arow * 32 + fq * 8];
            af[i][1] = *(const bf16x8*)&As[1][arow * 32 + fq * 8];
            const int brow = wc * 64 + i * 16 + fr;
            bfg[i][0] = *(const bf16x8*)&Bs[0][brow * 32 + fq * 8];
            bfg[i][1] = *(const bf16x8*)&Bs[1][brow * 32 + fq * 8];
        }
#pragma unroll
        for (int mi = 0; mi < 4; ++mi)
#pragma unroll
            for (int ni = 0; ni < 4; ++ni) {
                acc[mi][ni] = MFMA16(af[mi][0], bfg[ni][0], acc[mi][ni]);
                acc[mi][ni] = MFMA16(af[mi][0], bfg[ni][1], acc[mi][ni]);
                acc[mi][ni] = MFMA16(af[mi][1], bfg[ni][0], acc[mi][ni]);
            }
        __syncthreads();
    }

    const float* bias = (z == 0) ? bq : (z == 1) ? bk : bv;
#pragma unroll
    for (int mi = 0; mi < 4; ++mi) {
#pragma unroll
        for (int ni = 0; ni < 4; ++ni) {
            const int col = n0 + wc * 64 + ni * 16 + fr;
            const int hh = col >> 6, dd = col & 63;
#pragma unroll
            for (int j = 0; j < 4; ++j) {
                const int row = m0 + wr * 64 + mi * 16 + fq * 4 + j;
                float v = acc[mi][ni][j] + bias[col];
                const int nb = row >> 11, li = row & (SL - 1);
                const size_t off = (((size_t)nb * NH + hh) * SL + li) * HD + dd;
                if (z == 0) {
                    qh[off] = (bf16)(v * 0.125f);      // head_dim^-0.5
                } else if (z == 1) {
                    kh[off] = (bf16)v;
                } else {
                    vh[off] = (bf16)v;
                }
            }
        }
    }
}

// ------------------- output projection GEMM (hi/lo) -------------------
__global__ __launch_bounds__(256) void k_out_gemm(
    const bf16* __restrict__ ah, const bf16* __restrict__ al,
    const bf16* __restrict__ wh, const bf16* __restrict__ wl,
    const float* __restrict__ bo, float* __restrict__ out)
{
    __shared__ __attribute__((aligned(16))) bf16 As[2][128 * 32];
    __shared__ __attribute__((aligned(16))) bf16 Bs[2][128 * 32];

    const int m0 = blockIdx.x * 128;
    const int n0 = blockIdx.y * 128;
    const int tid = threadIdx.x, wave = tid >> 6, lane = tid & 63;
    const int wr = wave >> 1, wc = wave & 1;
    const int fr = lane & 15, fq = lane >> 4;

    const f32x4 z4 = {0.f, 0.f, 0.f, 0.f};
    f32x4 acc[4][4];
#pragma unroll
    for (int i = 0; i < 4; ++i)
#pragma unroll
        for (int j = 0; j < 4; ++j) acc[i][j] = z4;

#pragma unroll 1
    for (int kk = 0; kk < ED; kk += 32) {
#pragma unroll
        for (int r = 0; r < 2; ++r) {
            const int chunk = r * 256 + tid;
            const int row = chunk >> 2, c8 = (chunk & 3) * 8;
            const size_t ax = (size_t)(m0 + row) * ED + kk + c8;
            const size_t bx = (size_t)(n0 + row) * ED + kk + c8;
            const int db = (r * 256 + wave * 64) * 8;
            gl_lds16(ah + ax, &As[0][db]);
            gl_lds16(al + ax, &As[1][db]);
            gl_lds16(wh + bx, &Bs[0][db]);
            gl_lds16(wl + bx, &Bs[1][db]);
        }
        __syncthreads();
        bf16x8 af[4][2], bfg[4][2];
#pragma unroll
        for (int i = 0; i < 4; ++i) {
            const int arow = wr * 64 + i * 16 + fr;
            af[i][0] = *(const bf16x8*)&As[0][arow * 32 + fq * 8];
            af[i][1] = *(const bf16x8*)&As[1][arow * 32 + fq * 8];
            const int brow = wc * 64 + i * 16 + fr;
            bfg[i][0] = *(const bf16x8*)&Bs[0][brow * 32 + fq * 8];
            bfg[i][1] = *(const bf16x8*)&Bs[1][brow * 32 + fq * 8];
        }
#pragma unroll
        for (int mi = 0; mi < 4; ++mi)
#pragma unroll
            for (int ni = 0; ni < 4; ++ni) {
                acc[mi][ni] = MFMA16(af[mi][0], bfg[ni][0], acc[mi][ni]);
                acc[mi][ni] = MFMA16(af[mi][0], bfg[ni][1], acc[mi][ni]);
                acc[mi][ni] = MFMA16(af[mi][1], bfg[ni][0], acc[mi][ni]);
            }
        __syncthreads();
    }

#pragma unroll
    for (int mi = 0; mi < 4; ++mi)
#pragma unroll
        for (int ni = 0; ni < 4; ++ni) {
            const int col = n0 + wc * 64 + ni * 16 + fr;
#pragma unroll
            for (int j = 0; j < 4; ++j) {
                const int row = m0 + wr * 64 + mi * 16 + fq * 4 + j;
                out[(size_t)row * ED + col] = acc[mi][ni][j] + bo[col];
            }
        }
}

// ------------------- flash attention v6: QBLK=128, one barrier per K-tile -------------------
// Each wave owns TWO 16-row q-fragments (m=0,1). Ks and Vs both double-buffered:
// per tile {Vs[nxt]<-vr, issue K(kt+1)->Ks[nxt], vr<-V(kt+2), compute m=0,1 on [cur]}
// then ONE barrier. Ws per-wave buffer reused across m (wave-local, lgkm-ordered).
__global__ __launch_bounds__(256) void k_flash(
    const bf16* __restrict__ qh, const bf16* __restrict__ kh,
    const bf16* __restrict__ vh,
    const float* __restrict__ bias, const int* __restrict__ mask,
    bf16* __restrict__ ch, bf16* __restrict__ cl,
    float* __restrict__ mrow, float* __restrict__ srow)
{
    __shared__ __attribute__((aligned(16))) bf16 Ks[2][64 * 64];  // [key][d] swz, dbuf
    __shared__ __attribute__((aligned(16))) bf16 Vs[2][64 * 64];  // [d][key] swz, dbuf
    __shared__ __attribute__((aligned(16))) bf16 Ws[4][16 * 64];  // per-wave P, swz

    // block map: xcd gets 2 heads; within: qt sweeps, n fastest (bias L2 reuse)
    const int bid = blockIdx.x;
    const int xcd = bid & 7, local = bid >> 3;
    const int h = xcd * 2 + (local >> 6);
    const int rem = local & 63;
    const int qt = rem >> 2, n = rem & 3;

    const int tid = threadIdx.x, wave = tid >> 6, lane = tid & 63;
    const int fr = lane & 15, fq = lane >> 4;
    const int frx = fr & 7;
    const int q0 = qt * 128;
    const int qw = q0 + wave * 32;                  // wave's 32-row base
    const size_t hoff = ((size_t)n * NH + h) * SL * HD;
    const f32x4 z4 = {0.f, 0.f, 0.f, 0.f};

    // q fragments: two 16-row groups per wave
    bf16x8 qf0[2], qf1[2];
#pragma unroll
    for (int m = 0; m < 2; ++m) {
        const size_t qb = hoff + (size_t)(qw + m * 16 + fr) * HD + fq * 8;
        qf0[m] = *(const bf16x8*)(qh + qb);
        qf1[m] = *(const bf16x8*)(qh + qb + 32);
    }

    f32x4 o[2][4];
#pragma unroll
    for (int m = 0; m < 2; ++m)
#pragma unroll
        for (int f = 0; f < 4; ++f) o[m][f] = z4;
    float mj[2][4], sj[2][4];
#pragma unroll
    for (int m = 0; m < 2; ++m)
#pragma unroll
        for (int j = 0; j < 4; ++j) { mj[m][j] = -3e38f; sj[m][j] = 0.f; }

    const int* mkb = mask + n * SL;
    const float* bh = bias + (size_t)h * SL * SL;

    // ---- prologue ----
#pragma unroll
    for (int i = 0; i < 2; ++i) {
        const int li = i * 256 + tid;
        const int r = li >> 3, s = li & 7;
        gl_lds16(kh + hoff + (size_t)r * HD + (s ^ (r & 7)) * 8,
                 &Ks[0][(i * 256 + wave * 64) * 8]);
    }
    // V(0) -> regs -> Vs[0] (scatter-load scheme, known conflict-free)
    bf16x8 vr0 = *(const bf16x8*)(vh + hoff + (size_t)lane * HD + wave * 8);
    bf16x8 vr1 = *(const bf16x8*)(vh + hoff + (size_t)lane * HD + (wave + 4) * 8);
#pragma unroll
    for (int e = 0; e < 8; ++e) {
        const int d0 = wave * 8 + e, d1 = (wave + 4) * 8 + e;
        Vs[0][d0 * 64 + (((lane >> 3) ^ (d0 & 7)) << 3) + (lane & 7)] = vr0[e];
        Vs[0][d1 * 64 + (((lane >> 3) ^ (d1 & 7)) << 3) + (lane & 7)] = vr1[e];
    }
    // V(1) -> regs
    vr0 = *(const bf16x8*)(vh + hoff + (size_t)(64 + lane) * HD + wave * 8);
    vr1 = *(const bf16x8*)(vh + hoff + (size_t)(64 + lane) * HD + (wave + 4) * 8);
    int mkc[4];
#pragma unroll
    for (int nf = 0; nf < 4; ++nf) mkc[nf] = mkb[nf * 16 + fr];
    __syncthreads();   // drains K(0) DMA + Vs[0] writes

#pragma unroll 1
    for (int kt = 0; kt < 32; ++kt) {
        const int cur = kt & 1, nxt = cur ^ 1;
        const int kp1 = (kt < 31) ? kt + 1 : 31;
        const int kp2 = (kt < 30) ? kt + 2 : 31;

        // Vs[nxt] <- vr (V(kt+1)); Vs[cur] readers unaffected (other buffer)
#pragma unroll
        for (int e = 0; e < 8; ++e) {
            const int d0 = wave * 8 + e, d1 = (wave + 4) * 8 + e;
            Vs[nxt][d0 * 64 + (((lane >> 3) ^ (d0 & 7)) << 3) + (lane & 7)] = vr0[e];
            Vs[nxt][d1 * 64 + (((lane >> 3) ^ (d1 & 7)) << 3) + (lane & 7)] = vr1[e];
        }
        // issue K(kt+1) -> Ks[nxt]
#pragma unroll
        for (int i = 0; i < 2; ++i) {
            const int li = i * 256 + tid;
            const int r = li >> 3, s = li & 7;
            gl_lds16(kh + hoff + (size_t)(kp1 * 64 + r) * HD + (s ^ (r & 7)) * 8,
                     &Ks[nxt][(i * 256 + wave * 64) * 8]);
        }
        // V(kt+2) -> regs
        vr0 = *(const bf16x8*)(vh + hoff + (size_t)(kp2 * 64 + lane) * HD + wave * 8);
        vr1 = *(const bf16x8*)(vh + hoff + (size_t)(kp2 * 64 + lane) * HD + (wave + 4) * 8);
        // mask(kt+1)
        int mkn[4];
#pragma unroll
        for (int nf = 0; nf < 4; ++nf) mkn[nf] = mkb[kp1 * 64 + nf * 16 + fr];

        // ---- compute: two independent 16-row chains ----
#pragma unroll
        for (int m = 0; m < 2; ++m) {
            // bias loads first (vmem issues under the MFMAs)
            float bfr[4][4];
#pragma unroll
            for (int nf = 0; nf < 4; ++nf)
#pragma unroll
                for (int j = 0; j < 4; ++j)
                    bfr[nf][j] = bh[(size_t)(qw + m * 16 + fq * 4 + j) * SL
                                    + kt * 64 + nf * 16 + fr];

            f32x4 sf[4];
            __builtin_amdgcn_s_setprio(1);
#pragma unroll
            for (int nf = 0; nf < 4; ++nf) {
                const bf16* kp = &Ks[cur][(nf * 16 + fr) * 64];
                const bf16x8 b0 = *(const bf16x8*)&kp[(fq ^ frx) * 8];
                const bf16x8 b1 = *(const bf16x8*)&kp[((fq + 4) ^ frx) * 8];
                f32x4 a = z4;
                a = MFMA16(qf0[m], b0, a);
                a = MFMA16(qf1[m], b1, a);
                sf[nf] = a;
            }
            __builtin_amdgcn_s_setprio(0);

            // bias + mask
#pragma unroll
            for (int nf = 0; nf < 4; ++nf) {
                const bool mk = mkc[nf] != 0;
#pragma unroll
                for (int j = 0; j < 4; ++j) {
                    float s = sf[nf][j] + bfr[nf][j];
                    sf[nf][j] = mk ? -1e30f : s;
                }
            }
            // online softmax (rows wave-local; 16-lane butterfly)
            float tmax[4];
#pragma unroll
            for (int j = 0; j < 4; ++j)
                tmax[j] = fmaxf(fmaxf(sf[0][j], sf[1][j]), fmaxf(sf[2][j], sf[3][j]));
#pragma unroll
            for (int d = 1; d < 16; d <<= 1)
#pragma unroll
                for (int j = 0; j < 4; ++j)
                    tmax[j] = fmaxf(tmax[j], __shfl_xor(tmax[j], d));
            float scale[4];
#pragma unroll
            for (int j = 0; j < 4; ++j) {
                const float mn = fmaxf(mj[m][j], tmax[j]);
                scale[j] = __expf(mj[m][j] - mn);
                mj[m][j] = mn;
            }
            float rs[4] = {0.f, 0.f, 0.f, 0.f};
#pragma unroll
            for (int nf = 0; nf < 4; ++nf)
#pragma unroll
                for (int j = 0; j < 4; ++j) {
                    const float w = __expf(sf[nf][j] - mj[m][j]);
                    sf[nf][j] = w;
                    rs[j] += w;
                }
#pragma unroll
            for (int d = 1; d < 16; d <<= 1)
#pragma unroll
                for (int j = 0; j < 4; ++j)
                    rs[j] += __shfl_xor(rs[j], d);
#pragma unroll
            for (int j = 0; j < 4; ++j) sj[m][j] = sj[m][j] * scale[j] + rs[j];
#pragma unroll
            for (int f = 0; f < 4; ++f)
#pragma unroll
                for (int j = 0; j < 4; ++j) o[m][f][j] *= scale[j];

            // P -> per-wave swizzled LDS tile (wave-local; reused across m)
#pragma unroll
            for (int nf = 0; nf < 4; ++nf)
#pragma unroll
                for (int j = 0; j < 4; ++j) {
                    const int row = fq * 4 + j, col = nf * 16 + fr;
                    Ws[wave][row * 64 + (((col >> 3) ^ (row & 7)) << 3) + (fr & 7)] =
                        (bf16)sf[nf][j];
                }
            const bf16* wp = &Ws[wave][fr * 64];
            const bf16x8 wa0 = *(const bf16x8*)&wp[(fq ^ frx) * 8];
            const bf16x8 wa1 = *(const bf16x8*)&wp[((fq + 4) ^ frx) * 8];
            __builtin_amdgcn_s_setprio(1);
#pragma unroll
            for (int f = 0; f < 4; ++f) {
                const bf16* vp = &Vs[cur][(f * 16 + fr) * 64];
                const bf16x8 vb0 = *(const bf16x8*)&vp[(fq ^ frx) * 8];
                const bf16x8 vb1 = *(const bf16x8*)&vp[((fq + 4) ^ frx) * 8];
                o[m][f] = MFMA16(wa0, vb0, o[m][f]);
                o[m][f] = MFMA16(wa1, vb1, o[m][f]);
            }
            __builtin_amdgcn_s_setprio(0);
        }

#pragma unroll
        for (int nf = 0; nf < 4; ++nf) mkc[nf] = mkn[nf];
        __syncthreads();   // drains K(kt+1) DMA; fences Ks/Vs buffer swap
    }

    // epilogue: context (hi/lo) + row stats, both m
#pragma unroll
    for (int m = 0; m < 2; ++m) {
#pragma unroll
        for (int j = 0; j < 4; ++j) {
            const float inv = 1.0f / sj[m][j];
            const int row = n * SL + qw + m * 16 + fq * 4 + j;
#pragma unroll
            for (int f = 0; f < 4; ++f) {
                const float v = o[m][f][j] * inv;
                const size_t off = (size_t)row * ED + h * HD + f * 16 + fr;
                const bf16 hv = (bf16)v;
                ch[off] = hv;
                cl[off] = (bf16)(v - (float)hv);
            }
        }
        if (fr == 0) {
#pragma unroll
            for (int j = 0; j < 4; ++j) {
                const int r = qw + m * 16 + fq * 4 + j;
                mrow[((size_t)n * NH + h) * SL + r] = mj[m][j];
                srow[((size_t)n * NH + h) * SL + r] = sj[m][j];
            }
        }
    }
}

// ------------------- head-averaged weights v3: LDS-staged, reg accumulator -------------------
__global__ __launch_bounds__(256) void k_avg(
    const bf16* __restrict__ qh, const bf16* __restrict__ kh,
    const float* __restrict__ bias, const int* __restrict__ mask,
    const float* __restrict__ mrow, const float* __restrict__ srow,
    float* __restrict__ avg)
{
    __shared__ __attribute__((aligned(16))) bf16 Qs[2][64 * 64];  // 8KB x2
    __shared__ __attribute__((aligned(16))) bf16 Ks2[2][32 * 64]; // 4KB x2

    const int qt = blockIdx.x, kt = blockIdx.y;
    const int tid = threadIdx.x, wave = tid >> 6, lane = tid & 63;
    const int fr = lane & 15, fq = lane >> 4;
    const int frx = fr & 7;
    const int q0 = qt * 64, k0 = kt * 32;
    const int qr = q0 + wave * 16;
    const f32x4 z4 = {0.f, 0.f, 0.f, 0.f};

    f32x4 acc[4][2];
#pragma unroll
    for (int nn = 0; nn < 4; ++nn)
#pragma unroll
        for (int nf = 0; nf < 2; ++nf) acc[nn][nf] = z4;

    bool mk[4][2];
#pragma unroll
    for (int nn = 0; nn < 4; ++nn)
#pragma unroll
        for (int nf = 0; nf < 2; ++nf)
            mk[nn][nf] = mask[nn * SL + k0 + nf * 16 + fr] != 0;

    auto stage = [&](int hh, int nn2, int b) {
        const bf16* qb = qh + (((size_t)nn2 * NH + hh) * SL + q0) * HD;
        const bf16* kb = kh + (((size_t)nn2 * NH + hh) * SL + k0) * HD;
#pragma unroll
        for (int i = 0; i < 2; ++i) {
            const int li = i * 256 + tid;
            const int r = li >> 3, s = li & 7;
            gl_lds16(qb + (size_t)r * HD + (s ^ (r & 7)) * 8,
                     &Qs[b][(i * 256 + wave * 64) * 8]);
        }
        {
            const int r = tid >> 3, s = tid & 7;
            gl_lds16(kb + (size_t)r * HD + (s ^ (r & 7)) * 8,
                     &Ks2[b][(wave * 64) * 8]);
        }
    };

    stage(0, 0, 0);
    __syncthreads();

    int cur = 0;
#pragma unroll 1
    for (int h = 0; h < NH; ++h) {
        float bfr[2][4];
#pragma unroll
        for (int nf = 0; nf < 2; ++nf)
#pragma unroll
            for (int j = 0; j < 4; ++j)
                bfr[nf][j] = bias[((size_t)h * SL + qr + fq * 4 + j) * SL + k0 + nf * 16 + fr];

#pragma unroll
        for (int nn = 0; nn < 4; ++nn) {
            const int ih = h * 4 + nn;
            const int nxt = cur ^ 1;
            if (ih < 63) stage((ih + 1) >> 2, (ih + 1) & 3, nxt);

            const size_t sidx = ((size_t)nn * NH + h) * SL + qr + fq * 4;
            const f32x4 mv = *(const f32x4*)(mrow + sidx);
            const f32x4 sv = *(const f32x4*)(srow + sidx);
            float t2[2][4];
#pragma unroll
        for (int j = 0; j < 4; ++j) {
                const float lg = __logf(16.0f * sv[j]);
#pragma unroll
                for (int nf = 0; nf < 2; ++nf)
                    t2[nf][j] = mk[nn][nf] ? -1e30f : (bfr[nf][j] - mv[j] - lg);
            }

            const bf16* qp = &Qs[cur][(wave * 16 + fr) * 64];
            const bf16x8 qf0 = *(const bf16x8*)&qp[(fq ^ frx) * 8];
            const bf16x8 qf1 = *(const bf16x8*)&qp[((fq + 4) ^ frx) * 8];
#pragma unroll
            for (int nf = 0; nf < 2; ++nf) {
                const bf16* kp = &Ks2[cur][(nf * 16 + fr) * 64];
                const bf16x8 b0 = *(const bf16x8*)&kp[(fq ^ frx) * 8];
                const bf16x8 b1 = *(const bf16x8*)&kp[((fq + 4) ^ frx) * 8];
                f32x4 a = z4;
                a = MFMA16(qf0, b0, a);
                a = MFMA16(qf1, b1, a);
#pragma unroll
                for (int j = 0; j < 4; ++j)
                    acc[nn][nf][j] += __expf(a[j] + t2[nf][j]);
            }
            __syncthreads();
            cur = nxt;
        }
    }

#pragma unroll
    for (int nn = 0; nn < 4; ++nn)
#pragma unroll
        for (int j = 0; j < 4; ++j) {
            const size_t rowoff = ((size_t)nn * SL + qr + fq * 4 + j) * SL;
#pragma unroll
            for (int nf = 0; nf < 2; ++nf)
                avg[rowoff + k0 + nf * 16 + fr] = acc[nn][nf][j];
        }
}

// ------------------- launcher -------------------
extern "C" void kernel_launch(void* const* d_in, const int* in_sizes, int n_in,
                              void* d_out, int out_size, void* d_ws, size_t ws_size,
                              hipStream_t stream)
{
    (void)in_sizes; (void)n_in; (void)out_size; (void)ws_size;
    const float* query = (const float*)d_in[0];
    const float* bias  = (const float*)d_in[1];
    const int* mask = (const int*)d_in[2];
    const float* Wq = (const float*)d_in[3];
    const float* bq = (const float*)d_in[4];
    const float* Wk = (const float*)d_in[5];
    const float* bk = (const float*)d_in[6];
    const float* Wv = (const float*)d_in[7];
    const float* bv = (const float*)d_in[8];
    const float* Wo = (const float*)d_in[9];
    const float* bo = (const float*)d_in[10];
    float* out0 = (float*)d_out;                      // [N,L,E]
    float* out1 = out0 + (size_t)MR * ED;             // [N,L,L]

    char* p = (char*)d_ws;
    auto carve = [&](size_t bytes) {
        char* r = p;
        p += (bytes + 255) & ~(size_t)255;
        return r;
    };
    const size_t QKVB = (size_t)NB * NH * SL * HD * 2;   // 16.78 MB
    bf16* xh = (bf16*)carve((size_t)MR * ED * 2);
    bf16* xl = (bf16*)carve((size_t)MR * ED * 2);
    bf16* wh = (bf16*)carve((size_t)4 * ED * ED * 2);
    bf16* wl = (bf16*)carve((size_t)4 * ED * ED * 2);
    bf16* qh = (bf16*)carve(QKVB);
    bf16* kh = (bf16*)carve(QKVB);
    bf16* vh = (bf16*)carve(QKVB);
    float* mrow = (float*)carve((size_t)NB * NH * SL * 4);
    float* srow = (float*)carve((size_t)NB * NH * SL * 4);
    bf16* ch = (bf16*)carve((size_t)MR * ED * 2);
    bf16* cl = (bf16*)carve((size_t)MR * ED * 2);

    // 1. split inputs to hi/lo bf16
    {
        const int n4 = MR * ED / 4;
        k_split<<<(n4 + 255) / 256, 256, 0, stream>>>(query, xh, xl, n4);
        const int w4 = ED * ED / 4;
        const float* Ws4[4] = {Wq, Wk, Wv, Wo};
        for (int i = 0; i < 4; ++i)
            k_split<<<(w4 + 255) / 256, 256, 0, stream>>>(
                Ws4[i], wh + (size_t)i * ED * ED, wl + (size_t)i * ED * ED, w4);
    }
    // 2. QKV projections
    k_qkv_gemm<<<dim3(MR / 128, ED / 128, 3), 256, 0, stream>>>(
        xh, xl, wh, wl, bq, bk, bv, qh, kh, vh);
    // 3. flash attention + row stats + context (QBLK=128 -> 1024 blocks)
    k_flash<<<dim3(1024), 256, 0, stream>>>(
        qh, kh, vh, bias, mask, ch, cl, mrow, srow);
    // 4. head-averaged attention weights
    k_avg<<<dim3(SL / 64, SL / 32), 256, 0, stream>>>(
        qh, kh, bias, mask, mrow, srow, out1);
    // 5. output projection
    k_out_gemm<<<dim3(MR / 128, ED / 128), 256, 0, stream>>>(
        ch, cl, wh + (size_t)3 * ED * ED, wl + (size_t)3 * ED * ED, bo, out0);
}

// Round 13
// 660.036 us; speedup vs baseline: 2.5100x; 1.0829x over previous
//
#include <hip/hip_runtime.h>
#include <stdint.h>

typedef __bf16 bf16;
typedef __bf16 bf16x4 __attribute__((ext_vector_type(4)));
typedef __bf16 bf16x8 __attribute__((ext_vector_type(8)));
typedef float f32x4 __attribute__((ext_vector_type(4)));

#define MFMA16(a, b, c) __builtin_amdgcn_mfma_f32_16x16x32_bf16((a), (b), (c), 0, 0, 0)

static constexpr int NB = 4;      // batch
static constexpr int NH = 16;     // heads
static constexpr int SL = 2048;   // seq len
static constexpr int HD = 64;     // head dim
static constexpr int ED = 1024;   // embed
static constexpr int MR = NB * SL; // 8192 rows

__device__ __forceinline__ void gl_lds16(const void* g, void* l) {
    __builtin_amdgcn_global_load_lds(
        (const __attribute__((address_space(1))) unsigned int*)g,
        (__attribute__((address_space(3))) unsigned int*)l, 16, 0, 0);
}

// ------------------- f32 -> bf16 hi/lo split -------------------
__global__ void k_split(const float* __restrict__ src, bf16* __restrict__ hi,
                        bf16* __restrict__ lo, int n4) {
    int i = blockIdx.x * blockDim.x + threadIdx.x;
    if (i >= n4) return;
    const float4 v = ((const float4*)src)[i];
    float vv[4] = {v.x, v.y, v.z, v.w};
    bf16x4 hv, lv;
#pragma unroll
    for (int e = 0; e < 4; ++e) {
        bf16 h = (bf16)vv[e];
        hv[e] = h;
        lv[e] = (bf16)(vv[e] - (float)h);
    }
    ((bf16x4*)hi)[i] = hv;
    ((bf16x4*)lo)[i] = lv;
}

// ------------------- QKV projection GEMM (hi/lo inputs, bf16 outputs) -------------------
__global__ __launch_bounds__(256) void k_qkv_gemm(
    const bf16* __restrict__ xh, const bf16* __restrict__ xl,
    const bf16* __restrict__ wh, const bf16* __restrict__ wl,
    const float* __restrict__ bq, const float* __restrict__ bk,
    const float* __restrict__ bv,
    bf16* __restrict__ qh, bf16* __restrict__ kh, bf16* __restrict__ vh)
{
    __shared__ __attribute__((aligned(16))) bf16 As[2][128 * 32];
    __shared__ __attribute__((aligned(16))) bf16 Bs[2][128 * 32];

    const int z  = blockIdx.z;           // 0=q,1=k,2=v
    const int m0 = blockIdx.x * 128;
    const int n0 = blockIdx.y * 128;
    const int tid = threadIdx.x, wave = tid >> 6, lane = tid & 63;
    const int wr = wave >> 1, wc = wave & 1;
    const int fr = lane & 15, fq = lane >> 4;
    const bf16* Wh = wh + (size_t)z * ED * ED;
    const bf16* Wl = wl + (size_t)z * ED * ED;

    const f32x4 z4 = {0.f, 0.f, 0.f, 0.f};
    f32x4 acc[4][4];
#pragma unroll
    for (int i = 0; i < 4; ++i)
#pragma unroll
        for (int j = 0; j < 4; ++j) acc[i][j] = z4;

#pragma unroll 1
    for (int kk = 0; kk < ED; kk += 32) {
#pragma unroll
        for (int r = 0; r < 2; ++r) {
            const int chunk = r * 256 + tid;
            const int row = chunk >> 2, c8 = (chunk & 3) * 8;
            const size_t ax = (size_t)(m0 + row) * ED + kk + c8;
            const size_t bx = (size_t)(n0 + row) * ED + kk + c8;
            const int db = (r * 256 + wave * 64) * 8;   // wave-uniform LDS base
            gl_lds16(xh + ax, &As[0][db]);
            gl_lds16(xl + ax, &As[1][db]);
            gl_lds16(Wh + bx, &Bs[0][db]);
            gl_lds16(Wl + bx, &Bs[1][db]);
        }
        __syncthreads();
        bf16x8 af[4][2], bfg[4][2];
#pragma unroll
        for (int i = 0; i < 4; ++i) {
            const int arow = wr * 64 + i * 16 + fr;
            af[i][0] = *(const bf16x8*)&As[0][arow * 32 + fq * 8];
            af[i][1] = *(const bf16x8*)&As[1][arow * 32 + fq * 8];
            const int brow = wc * 64 + i * 16 + fr;
            bfg[i][0] = *(const bf16x8*)&Bs[0][brow * 32 + fq * 8];
            bfg[i][1] = *(const bf16x8*)&Bs[1][brow * 32 + fq * 8];
        }
#pragma unroll
        for (int mi = 0; mi < 4; ++mi)
#pragma unroll
            for (int ni = 0; ni < 4; ++ni) {
                acc[mi][ni] = MFMA16(af[mi][0], bfg[ni][0], acc[mi][ni]);
                acc[mi][ni] = MFMA16(af[mi][0], bfg[ni][1], acc[mi][ni]);
                acc[mi][ni] = MFMA16(af[mi][1], bfg[ni][0], acc[mi][ni]);
            }
        __syncthreads();
    }

    const float* bias = (z == 0) ? bq : (z == 1) ? bk : bv;
#pragma unroll
    for (int mi = 0; mi < 4; ++mi) {
#pragma unroll
        for (int ni = 0; ni < 4; ++ni) {
            const int col = n0 + wc * 64 + ni * 16 + fr;
            const int hh = col >> 6, dd = col & 63;
#pragma unroll
            for (int j = 0; j < 4; ++j) {
                const int row = m0 + wr * 64 + mi * 16 + fq * 4 + j;
                float v = acc[mi][ni][j] + bias[col];
                const int nb = row >> 11, li = row & (SL - 1);
                const size_t off = (((size_t)nb * NH + hh) * SL + li) * HD + dd;
                if (z == 0) {
                    qh[off] = (bf16)(v * 0.125f);      // head_dim^-0.5
                } else if (z == 1) {
                    kh[off] = (bf16)v;
                } else {
                    vh[off] = (bf16)v;
                }
            }
        }
    }
}

// ------------------- output projection GEMM (hi/lo) -------------------
__global__ __launch_bounds__(256) void k_out_gemm(
    const bf16* __restrict__ ah, const bf16* __restrict__ al,
    const bf16* __restrict__ wh, const bf16* __restrict__ wl,
    const float* __restrict__ bo, float* __restrict__ out)
{
    __shared__ __attribute__((aligned(16))) bf16 As[2][128 * 32];
    __shared__ __attribute__((aligned(16))) bf16 Bs[2][128 * 32];

    const int m0 = blockIdx.x * 128;
    const int n0 = blockIdx.y * 128;
    const int tid = threadIdx.x, wave = tid >> 6, lane = tid & 63;
    const int wr = wave >> 1, wc = wave & 1;
    const int fr = lane & 15, fq = lane >> 4;

    const f32x4 z4 = {0.f, 0.f, 0.f, 0.f};
    f32x4 acc[4][4];
#pragma unroll
    for (int i = 0; i < 4; ++i)
#pragma unroll
        for (int j = 0; j < 4; ++j) acc[i][j] = z4;

#pragma unroll 1
    for (int kk = 0; kk < ED; kk += 32) {
#pragma unroll
        for (int r = 0; r < 2; ++r) {
            const int chunk = r * 256 + tid;
            const int row = chunk >> 2, c8 = (chunk & 3) * 8;
            const size_t ax = (size_t)(m0 + row) * ED + kk + c8;
            const size_t bx = (size_t)(n0 + row) * ED + kk + c8;
            const int db = (r * 256 + wave * 64) * 8;
            gl_lds16(ah + ax, &As[0][db]);
            gl_lds16(al + ax, &As[1][db]);
            gl_lds16(wh + bx, &Bs[0][db]);
            gl_lds16(wl + bx, &Bs[1][db]);
        }
        __syncthreads();
        bf16x8 af[4][2], bfg[4][2];
#pragma unroll
        for (int i = 0; i < 4; ++i) {
            const int arow = wr * 64 + i * 16 + fr;
            af[i][0] = *(const bf16x8*)&As[0][arow * 32 + fq * 8];
            af[i][1] = *(const bf16x8*)&As[1][arow * 32 + fq * 8];
            const int brow = wc * 64 + i * 16 + fr;
            bfg[i][0] = *(const bf16x8*)&Bs[0][brow * 32 + fq * 8];
            bfg[i][1] = *(const bf16x8*)&Bs[1][brow * 32 + fq * 8];
        }
#pragma unroll
        for (int mi = 0; mi < 4; ++mi)
#pragma unroll
            for (int ni = 0; ni < 4; ++ni) {
                acc[mi][ni] = MFMA16(af[mi][0], bfg[ni][0], acc[mi][ni]);
                acc[mi][ni] = MFMA16(af[mi][0], bfg[ni][1], acc[mi][ni]);
                acc[mi][ni] = MFMA16(af[mi][1], bfg[ni][0], acc[mi][ni]);
            }
        __syncthreads();
    }

#pragma unroll
    for (int mi = 0; mi < 4; ++mi)
#pragma unroll
        for (int ni = 0; ni < 4; ++ni) {
            const int col = n0 + wc * 64 + ni * 16 + fr;
#pragma unroll
            for (int j = 0; j < 4; ++j) {
                const int row = m0 + wr * 64 + mi * 16 + fq * 4 + j;
                out[(size_t)row * ED + col] = acc[mi][ni][j] + bo[col];
            }
        }
}

// ------------------- flash attention v7: QBLK=128 + defer-max + lazy sum -------------------
// Common path per tile: NO cross-lane ops (no butterflies, no rescale). Rescale
// triggers only when a lane's tile-max exceeds mj+8 (checked via __any).
// sj is lane-local partial, reduced once in the epilogue.
__global__ __launch_bounds__(256) void k_flash(
    const bf16* __restrict__ qh, const bf16* __restrict__ kh,
    const bf16* __restrict__ vh,
    const float* __restrict__ bias, const int* __restrict__ mask,
    bf16* __restrict__ ch, bf16* __restrict__ cl,
    float* __restrict__ mrow, float* __restrict__ srow)
{
    __shared__ __attribute__((aligned(16))) bf16 Ks[2][64 * 64];  // [key][d] swz, dbuf
    __shared__ __attribute__((aligned(16))) bf16 Vs[2][64 * 64];  // [d][key] swz, dbuf
    __shared__ __attribute__((aligned(16))) bf16 Ws[4][16 * 64];  // per-wave P, swz

    // block map: xcd gets 2 heads; within: qt sweeps, n fastest (bias L2 reuse)
    const int bid = blockIdx.x;
    const int xcd = bid & 7, local = bid >> 3;
    const int h = xcd * 2 + (local >> 6);
    const int rem = local & 63;
    const int qt = rem >> 2, n = rem & 3;

    const int tid = threadIdx.x, wave = tid >> 6, lane = tid & 63;
    const int fr = lane & 15, fq = lane >> 4;
    const int frx = fr & 7;
    const int q0 = qt * 128;
    const int qw = q0 + wave * 32;                  // wave's 32-row base
    const size_t hoff = ((size_t)n * NH + h) * SL * HD;
    const f32x4 z4 = {0.f, 0.f, 0.f, 0.f};

    // q fragments: two 16-row groups per wave
    bf16x8 qf0[2], qf1[2];
#pragma unroll
    for (int m = 0; m < 2; ++m) {
        const size_t qb = hoff + (size_t)(qw + m * 16 + fr) * HD + fq * 8;
        qf0[m] = *(const bf16x8*)(qh + qb);
        qf1[m] = *(const bf16x8*)(qh + qb + 32);
    }

    f32x4 o[2][4];
#pragma unroll
    for (int m = 0; m < 2; ++m)
#pragma unroll
        for (int f = 0; f < 4; ++f) o[m][f] = z4;
    float mj[2][4], sj[2][4];   // sj: LANE-LOCAL partial sums
#pragma unroll
    for (int m = 0; m < 2; ++m)
#pragma unroll
        for (int j = 0; j < 4; ++j) { mj[m][j] = -3e38f; sj[m][j] = 0.f; }

    const int* mkb = mask + n * SL;
    const float* bh = bias + (size_t)h * SL * SL;

    // ---- prologue ----
#pragma unroll
    for (int i = 0; i < 2; ++i) {
        const int li = i * 256 + tid;
        const int r = li >> 3, s = li & 7;
        gl_lds16(kh + hoff + (size_t)r * HD + (s ^ (r & 7)) * 8,
                 &Ks[0][(i * 256 + wave * 64) * 8]);
    }
    bf16x8 vr0 = *(const bf16x8*)(vh + hoff + (size_t)lane * HD + wave * 8);
    bf16x8 vr1 = *(const bf16x8*)(vh + hoff + (size_t)lane * HD + (wave + 4) * 8);
#pragma unroll
    for (int e = 0; e < 8; ++e) {
        const int d0 = wave * 8 + e, d1 = (wave + 4) * 8 + e;
        Vs[0][d0 * 64 + (((lane >> 3) ^ (d0 & 7)) << 3) + (lane & 7)] = vr0[e];
        Vs[0][d1 * 64 + (((lane >> 3) ^ (d1 & 7)) << 3) + (lane & 7)] = vr1[e];
    }
    vr0 = *(const bf16x8*)(vh + hoff + (size_t)(64 + lane) * HD + wave * 8);
    vr1 = *(const bf16x8*)(vh + hoff + (size_t)(64 + lane) * HD + (wave + 4) * 8);
    int mkc[4];
#pragma unroll
    for (int nf = 0; nf < 4; ++nf) mkc[nf] = mkb[nf * 16 + fr];
    __syncthreads();   // drains K(0) DMA + Vs[0] writes

#pragma unroll 1
    for (int kt = 0; kt < 32; ++kt) {
        const int cur = kt & 1, nxt = cur ^ 1;
        const int kp1 = (kt < 31) ? kt + 1 : 31;
        const int kp2 = (kt < 30) ? kt + 2 : 31;

        // Vs[nxt] <- vr (V(kt+1))
#pragma unroll
        for (int e = 0; e < 8; ++e) {
            const int d0 = wave * 8 + e, d1 = (wave + 4) * 8 + e;
            Vs[nxt][d0 * 64 + (((lane >> 3) ^ (d0 & 7)) << 3) + (lane & 7)] = vr0[e];
            Vs[nxt][d1 * 64 + (((lane >> 3) ^ (d1 & 7)) << 3) + (lane & 7)] = vr1[e];
        }
        // issue K(kt+1) -> Ks[nxt]
#pragma unroll
        for (int i = 0; i < 2; ++i) {
            const int li = i * 256 + tid;
            const int r = li >> 3, s = li & 7;
            gl_lds16(kh + hoff + (size_t)(kp1 * 64 + r) * HD + (s ^ (r & 7)) * 8,
                     &Ks[nxt][(i * 256 + wave * 64) * 8]);
        }
        // V(kt+2) -> regs
        vr0 = *(const bf16x8*)(vh + hoff + (size_t)(kp2 * 64 + lane) * HD + wave * 8);
        vr1 = *(const bf16x8*)(vh + hoff + (size_t)(kp2 * 64 + lane) * HD + (wave + 4) * 8);
        int mkn[4];
#pragma unroll
        for (int nf = 0; nf < 4; ++nf) mkn[nf] = mkb[kp1 * 64 + nf * 16 + fr];

        // ---- compute: two independent 16-row chains ----
#pragma unroll
        for (int m = 0; m < 2; ++m) {
            float bfr[4][4];
#pragma unroll
            for (int nf = 0; nf < 4; ++nf)
#pragma unroll
                for (int j = 0; j < 4; ++j)
                    bfr[nf][j] = bh[(size_t)(qw + m * 16 + fq * 4 + j) * SL
                                    + kt * 64 + nf * 16 + fr];

            f32x4 sf[4];
            __builtin_amdgcn_s_setprio(1);
#pragma unroll
            for (int nf = 0; nf < 4; ++nf) {
                const bf16* kp = &Ks[cur][(nf * 16 + fr) * 64];
                const bf16x8 b0 = *(const bf16x8*)&kp[(fq ^ frx) * 8];
                const bf16x8 b1 = *(const bf16x8*)&kp[((fq + 4) ^ frx) * 8];
                f32x4 a = z4;
                a = MFMA16(qf0[m], b0, a);
                a = MFMA16(qf1[m], b1, a);
                sf[nf] = a;
            }
            __builtin_amdgcn_s_setprio(0);

            // bias + mask
#pragma unroll
            for (int nf = 0; nf < 4; ++nf) {
                const bool mk = mkc[nf] != 0;
#pragma unroll
                for (int j = 0; j < 4; ++j) {
                    float s = sf[nf][j] + bfr[nf][j];
                    sf[nf][j] = mk ? -1e30f : s;
                }
            }

            // ---- defer-max online softmax ----
            // lane-local max over the 4 columns this lane owns
            float tmax[4];
#pragma unroll
            for (int j = 0; j < 4; ++j)
                tmax[j] = fmaxf(fmaxf(sf[0][j], sf[1][j]), fmaxf(sf[2][j], sf[3][j]));
            bool need = false;
#pragma unroll
            for (int j = 0; j < 4; ++j)
                need = need || (tmax[j] > mj[m][j] + 8.0f);
            if (__any(need)) {
                // rare path: full row-max butterfly + rescale
#pragma unroll
                for (int d = 1; d < 16; d <<= 1)
#pragma unroll
                    for (int j = 0; j < 4; ++j)
                        tmax[j] = fmaxf(tmax[j], __shfl_xor(tmax[j], d));
#pragma unroll
                for (int j = 0; j < 4; ++j) {
                    const float mn = fmaxf(mj[m][j], tmax[j]);
                    const float scale = __expf(mj[m][j] - mn);
                    mj[m][j] = mn;
                    sj[m][j] *= scale;
#pragma unroll
                    for (int f = 0; f < 4; ++f) o[m][f][j] *= scale;
                }
            }
            // common path: exp + lane-local accumulate (no cross-lane ops)
#pragma unroll
            for (int nf = 0; nf < 4; ++nf)
#pragma unroll
                for (int j = 0; j < 4; ++j) {
                    const float w = __expf(sf[nf][j] - mj[m][j]);
                    sf[nf][j] = w;
                    sj[m][j] += w;
                }

            // P -> per-wave swizzled LDS tile (wave-local; reused across m)
#pragma unroll
            for (int nf = 0; nf < 4; ++nf)
#pragma unroll
                for (int j = 0; j < 4; ++j) {
                    const int row = fq * 4 + j, col = nf * 16 + fr;
                    Ws[wave][row * 64 + (((col >> 3) ^ (row & 7)) << 3) + (fr & 7)] =
                        (bf16)sf[nf][j];
                }
            const bf16* wp = &Ws[wave][fr * 64];
            const bf16x8 wa0 = *(const bf16x8*)&wp[(fq ^ frx) * 8];
            const bf16x8 wa1 = *(const bf16x8*)&wp[((fq + 4) ^ frx) * 8];
            __builtin_amdgcn_s_setprio(1);
#pragma unroll
            for (int f = 0; f < 4; ++f) {
                const bf16* vp = &Vs[cur][(f * 16 + fr) * 64];
                const bf16x8 vb0 = *(const bf16x8*)&vp[(fq ^ frx) * 8];
                const bf16x8 vb1 = *(const bf16x8*)&vp[((fq + 4) ^ frx) * 8];
                o[m][f] = MFMA16(wa0, vb0, o[m][f]);
                o[m][f] = MFMA16(wa1, vb1, o[m][f]);
            }
            __builtin_amdgcn_s_setprio(0);
        }

#pragma unroll
        for (int nf = 0; nf < 4; ++nf) mkc[nf] = mkn[nf];
        __syncthreads();   // drains K(kt+1) DMA; fences Ks/Vs buffer swap
    }

    // epilogue: reduce lane-local sj across the 16-lane row group (once)
#pragma unroll
    for (int m = 0; m < 2; ++m)
#pragma unroll
        for (int d = 1; d < 16; d <<= 1)
#pragma unroll
            for (int j = 0; j < 4; ++j)
                sj[m][j] += __shfl_xor(sj[m][j], d);

    // context (hi/lo) + row stats, both m
#pragma unroll
    for (int m = 0; m < 2; ++m) {
#pragma unroll
        for (int j = 0; j < 4; ++j) {
            const float inv = 1.0f / sj[m][j];
            const int row = n * SL + qw + m * 16 + fq * 4 + j;
#pragma unroll
            for (int f = 0; f < 4; ++f) {
                const float v = o[m][f][j] * inv;
                const size_t off = (size_t)row * ED + h * HD + f * 16 + fr;
                const bf16 hv = (bf16)v;
                ch[off] = hv;
                cl[off] = (bf16)(v - (float)hv);
            }
        }
        if (fr == 0) {
#pragma unroll
            for (int j = 0; j < 4; ++j) {
                const int r = qw + m * 16 + fq * 4 + j;
                mrow[((size_t)n * NH + h) * SL + r] = mj[m][j];
                srow[((size_t)n * NH + h) * SL + r] = sj[m][j];
            }
        }
    }
}

// ------------------- head-averaged weights v3: LDS-staged, reg accumulator -------------------
__global__ __launch_bounds__(256) void k_avg(
    const bf16* __restrict__ qh, const bf16* __restrict__ kh,
    const float* __restrict__ bias, const int* __restrict__ mask,
    const float* __restrict__ mrow, const float* __restrict__ srow,
    float* __restrict__ avg)
{
    __shared__ __attribute__((aligned(16))) bf16 Qs[2][64 * 64];  // 8KB x2
    __shared__ __attribute__((aligned(16))) bf16 Ks2[2][32 * 64]; // 4KB x2

    const int qt = blockIdx.x, kt = blockIdx.y;
    const int tid = threadIdx.x, wave = tid >> 6, lane = tid & 63;
    const int fr = lane & 15, fq = lane >> 4;
    const int frx = fr & 7;
    const int q0 = qt * 64, k0 = kt * 32;
    const int qr = q0 + wave * 16;
    const f32x4 z4 = {0.f, 0.f, 0.f, 0.f};

    f32x4 acc[4][2];
#pragma unroll
    for (int nn = 0; nn < 4; ++nn)
#pragma unroll
        for (int nf = 0; nf < 2; ++nf) acc[nn][nf] = z4;

    bool mk[4][2];
#pragma unroll
    for (int nn = 0; nn < 4; ++nn)
#pragma unroll
        for (int nf = 0; nf < 2; ++nf)
            mk[nn][nf] = mask[nn * SL + k0 + nf * 16 + fr] != 0;

    auto stage = [&](int hh, int nn2, int b) {
        const bf16* qb = qh + (((size_t)nn2 * NH + hh) * SL + q0) * HD;
        const bf16* kb = kh + (((size_t)nn2 * NH + hh) * SL + k0) * HD;
#pragma unroll
        for (int i = 0; i < 2; ++i) {
            const int li = i * 256 + tid;
            const int r = li >> 3, s = li & 7;
            gl_lds16(qb + (size_t)r * HD + (s ^ (r & 7)) * 8,
                     &Qs[b][(i * 256 + wave * 64) * 8]);
        }
        {
            const int r = tid >> 3, s = tid & 7;
            gl_lds16(kb + (size_t)r * HD + (s ^ (r & 7)) * 8,
                     &Ks2[b][(wave * 64) * 8]);
        }
    };

    stage(0, 0, 0);
    __syncthreads();

    int cur = 0;
#pragma unroll 1
    for (int h = 0; h < NH; ++h) {
        float bfr[2][4];
#pragma unroll
        for (int nf = 0; nf < 2; ++nf)
#pragma unroll
            for (int j = 0; j < 4; ++j)
                bfr[nf][j] = bias[((size_t)h * SL + qr + fq * 4 + j) * SL + k0 + nf * 16 + fr];

#pragma unroll
        for (int nn = 0; nn < 4; ++nn) {
            const int ih = h * 4 + nn;
            const int nxt = cur ^ 1;
            if (ih < 63) stage((ih + 1) >> 2, (ih + 1) & 3, nxt);

            const size_t sidx = ((size_t)nn * NH + h) * SL + qr + fq * 4;
            const f32x4 mv = *(const f32x4*)(mrow + sidx);
            const f32x4 sv = *(const f32x4*)(srow + sidx);
            float t2[2][4];
#pragma unroll
        for (int j = 0; j < 4; ++j) {
                const float lg = __logf(16.0f * sv[j]);
#pragma unroll
                for (int nf = 0; nf < 2; ++nf)
                    t2[nf][j] = mk[nn][nf] ? -1e30f : (bfr[nf][j] - mv[j] - lg);
            }

            const bf16* qp = &Qs[cur][(wave * 16 + fr) * 64];
            const bf16x8 qf0 = *(const bf16x8*)&qp[(fq ^ frx) * 8];
            const bf16x8 qf1 = *(const bf16x8*)&qp[((fq + 4) ^ frx) * 8];
#pragma unroll
            for (int nf = 0; nf < 2; ++nf) {
                const bf16* kp = &Ks2[cur][(nf * 16 + fr) * 64];
                const bf16x8 b0 = *(const bf16x8*)&kp[(fq ^ frx) * 8];
                const bf16x8 b1 = *(const bf16x8*)&kp[((fq + 4) ^ frx) * 8];
                f32x4 a = z4;
                a = MFMA16(qf0, b0, a);
                a = MFMA16(qf1, b1, a);
#pragma unroll
                for (int j = 0; j < 4; ++j)
                    acc[nn][nf][j] += __expf(a[j] + t2[nf][j]);
            }
            __syncthreads();
            cur = nxt;
        }
    }

#pragma unroll
    for (int nn = 0; nn < 4; ++nn)
#pragma unroll
        for (int j = 0; j < 4; ++j) {
            const size_t rowoff = ((size_t)nn * SL + qr + fq * 4 + j) * SL;
#pragma unroll
            for (int nf = 0; nf < 2; ++nf)
                avg[rowoff + k0 + nf * 16 + fr] = acc[nn][nf][j];
        }
}

// ------------------- launcher -------------------
extern "C" void kernel_launch(void* const* d_in, const int* in_sizes, int n_in,
                              void* d_out, int out_size, void* d_ws, size_t ws_size,
                              hipStream_t stream)
{
    (void)in_sizes; (void)n_in; (void)out_size; (void)ws_size;
    const float* query = (const float*)d_in[0];
    const float* bias  = (const float*)d_in[1];
    const int* mask = (const int*)d_in[2];
    const float* Wq = (const float*)d_in[3];
    const float* bq = (const float*)d_in[4];
    const float* Wk = (const float*)d_in[5];
    const float* bk = (const float*)d_in[6];
    const float* Wv = (const float*)d_in[7];
    const float* bv = (const float*)d_in[8];
    const float* Wo = (const float*)d_in[9];
    const float* bo = (const float*)d_in[10];
    float* out0 = (float*)d_out;                      // [N,L,E]
    float* out1 = out0 + (size_t)MR * ED;             // [N,L,L]

    char* p = (char*)d_ws;
    auto carve = [&](size_t bytes) {
        char* r = p;
        p += (bytes + 255) & ~(size_t)255;
        return r;
    };
    const size_t QKVB = (size_t)NB * NH * SL * HD * 2;   // 16.78 MB
    bf16* xh = (bf16*)carve((size_t)MR * ED * 2);
    bf16* xl = (bf16*)carve((size_t)MR * ED * 2);
    bf16* wh = (bf16*)carve((size_t)4 * ED * ED * 2);
    bf16* wl = (bf16*)carve((size_t)4 * ED * ED * 2);
    bf16* qh = (bf16*)carve(QKVB);
    bf16* kh = (bf16*)carve(QKVB);
    bf16* vh = (bf16*)carve(QKVB);
    float* mrow = (float*)carve((size_t)NB * NH * SL * 4);
    float* srow = (float*)carve((size_t)NB * NH * SL * 4);
    bf16* ch = (bf16*)carve((size_t)MR * ED * 2);
    bf16* cl = (bf16*)carve((size_t)MR * ED * 2);

    // 1. split inputs to hi/lo bf16
    {
        const int n4 = MR * ED / 4;
        k_split<<<(n4 + 255) / 256, 256, 0, stream>>>(query, xh, xl, n4);
        const int w4 = ED * ED / 4;
        const float* Ws4[4] = {Wq, Wk, Wv, Wo};
        for (int i = 0; i < 4; ++i)
            k_split<<<(w4 + 255) / 256, 256, 0, stream>>>(
                Ws4[i], wh + (size_t)i * ED * ED, wl + (size_t)i * ED * ED, w4);
    }
    // 2. QKV projections
    k_qkv_gemm<<<dim3(MR / 128, ED / 128, 3), 256, 0, stream>>>(
        xh, xl, wh, wl, bq, bk, bv, qh, kh, vh);
    // 3. flash attention + row stats + context (QBLK=128 -> 1024 blocks)
    k_flash<<<dim3(1024), 256, 0, stream>>>(
        qh, kh, vh, bias, mask, ch, cl, mrow, srow);
    // 4. head-averaged attention weights
    k_avg<<<dim3(SL / 64, SL / 32), 256, 0, stream>>>(
        qh, kh, bias, mask, mrow, srow, out1);
    // 5. output projection
    k_out_gemm<<<dim3(MR / 128, ED / 128), 256, 0, stream>>>(
        ch, cl, wh + (size_t)3 * ED * ED, wl + (size_t)3 * ED * ED, bo, out0);
}